// Round 1
// baseline (1594.350 us; speedup 1.0000x reference)
//
#include <hip/hip_runtime.h>
#include <math.h>

typedef __bf16 bf16_t;
typedef __bf16 bf16x8 __attribute__((ext_vector_type(8)));
typedef float f32x4 __attribute__((ext_vector_type(4)));

#define DEV __device__ __forceinline__

constexpr int Bc = 2, Tc = 2048, Cc = 512, Hc = 8, FFNc = 2048, Lc = 4;
constexpr int Mc = Bc * Tc;           // 4096 rows
constexpr float kSCALE = 0.125f;      // KD^-0.5, KD=64
constexpr float kEPS = 1e-6f;

// ---------------- workspace layout (bytes) ----------------
constexpr size_t OFF_WQKVG = 0;                                    // L*2048*512 bf16 (q,k,v,g packed, N-major rows, K cont.)
constexpr size_t OFF_WO    = OFF_WQKVG + (size_t)Lc*2048*512*2;    // L*512*512 bf16
constexpr size_t OFF_W1    = OFF_WO    + (size_t)Lc*512*512*2;     // L*2048*512 bf16
constexpr size_t OFF_W2    = OFF_W1    + (size_t)Lc*2048*512*2;    // L*512*2048 bf16
constexpr size_t OFF_BQKVG = OFF_W2    + (size_t)Lc*512*2048*2;    // L*2048 f32
constexpr size_t OFF_TABC  = OFF_BQKVG + (size_t)Lc*2048*4;        // 2048*32 f32
constexpr size_t OFF_TABS  = OFF_TABC  + (size_t)Tc*32*4;
constexpr size_t OFF_HLN   = OFF_TABS  + (size_t)Tc*32*4;          // 4096*2048 bf16 (LN out; also FFN-mid LN out)
constexpr size_t OFF_QKVG  = OFF_HLN   + (size_t)Mc*2048*2;        // 4096*2048 f32 (qkvg; reused as FFN h1)
constexpr size_t OFF_QR    = OFF_QKVG  + (size_t)Mc*2048*4;        // (B,H,T,64) bf16
constexpr size_t OFF_KR    = OFF_QR    + (size_t)Bc*Hc*Tc*64*2;
constexpr size_t OFF_VR    = OFF_KR    + (size_t)Bc*Hc*Tc*64*2;
constexpr size_t OFF_AO    = OFF_VR    + (size_t)Bc*Hc*Tc*64*2;    // 4096*512 f32 retention out
constexpr size_t OFF_GATED = OFF_AO    + (size_t)Mc*512*4;         // 4096*512 bf16
// total ~103.5 MB

DEV float gelu_f(float x) { return 0.5f * x * (1.0f + erff(x * 0.70710678118654752f)); }

DEV void async_load16(const void* g, void* l) {
  // LDS dest: wave-uniform base; HW scatters lane*16B (m97 pattern, width=16)
  __builtin_amdgcn_global_load_lds((const __attribute__((address_space(1))) unsigned int*)g,
                                   (__attribute__((address_space(3))) unsigned int*)l, 16, 0, 0);
}

// ---------------- weight transpose+pack: dst[n*K+k] = bf16(src[k*N+n]) ----------------
__global__ __launch_bounds__(256) void transpose_pack_k(const float* __restrict__ src, bf16_t* __restrict__ dst,
                                                        int K, int N, size_t src_lstride, size_t dst_lstride) {
  __shared__ float tile[32][33];
  src += blockIdx.z * src_lstride;
  dst += blockIdx.z * dst_lstride;
  const int n0 = blockIdx.x * 32, k0 = blockIdx.y * 32;
  const int tx = threadIdx.x, ty = threadIdx.y;  // (32,8)
#pragma unroll
  for (int j = 0; j < 32; j += 8) tile[ty + j][tx] = src[(size_t)(k0 + ty + j) * N + n0 + tx];
  __syncthreads();
#pragma unroll
  for (int j = 0; j < 32; j += 8) dst[(size_t)(n0 + ty + j) * K + k0 + tx] = (bf16_t)tile[tx][ty + j];
}

__global__ __launch_bounds__(256) void biaspack_k(const float* __restrict__ bq, const float* __restrict__ bk,
                                                  const float* __restrict__ bv, const float* __restrict__ bg,
                                                  float* __restrict__ outp) {
  const int tid = blockIdx.x * 256 + threadIdx.x;  // L*2048 = 8192
  const int l = tid >> 11, n = tid & 2047;
  const float* srcs[4] = {bq, bk, bv, bg};
  outp[tid] = srcs[n >> 9][l * 512 + (n & 511)];
}

__global__ __launch_bounds__(256) void trig_k(float* __restrict__ tc, float* __restrict__ ts) {
  const int tid = blockIdx.x * 256 + threadIdx.x;  // 65536
  const int t = tid >> 5, i = tid & 31;
  const float angle = powf(10000.f, -(float)i / 31.f);
  const float a = (float)t * angle;
  tc[tid] = cosf(a);
  ts[tid] = sinf(a);
}

// ---------------- LayerNorm (no affine) fp32 in -> bf16 out ----------------
template <int NC>
__global__ __launch_bounds__(256) void ln_k(const float* __restrict__ in, bf16_t* __restrict__ out) {
  constexpr int PT = NC / 256;
  const int row = blockIdx.x;
  const float* rp = in + (size_t)row * NC;
  float v[PT], s = 0.f, sq = 0.f;
#pragma unroll
  for (int i = 0; i < PT; ++i) { v[i] = rp[threadIdx.x + i * 256]; s += v[i]; sq += v[i] * v[i]; }
#pragma unroll
  for (int m = 1; m < 64; m <<= 1) { s += __shfl_xor(s, m); sq += __shfl_xor(sq, m); }
  __shared__ float red[8];
  const int wave = threadIdx.x >> 6, lane = threadIdx.x & 63;
  if (lane == 0) { red[wave] = s; red[4 + wave] = sq; }
  __syncthreads();
  s = red[0] + red[1] + red[2] + red[3];
  sq = red[4] + red[5] + red[6] + red[7];
  const float mean = s * (1.f / NC);
  const float inv = rsqrtf(sq * (1.f / NC) - mean * mean + kEPS);
  bf16_t* op = out + (size_t)row * NC;
#pragma unroll
  for (int i = 0; i < PT; ++i) op[threadIdx.x + i * 256] = (bf16_t)((v[i] - mean) * inv);
}

// ---------------- GEMM: out(f32) = epi(A(bf16, MxK) @ Bt(bf16, NxK)^T + bias) ----------------
// epi: 1=gelu, 2=gelu + SCALE on cols [512,1024) (packed k-chunk), 3=gelu + residual add
template <int BM, int BN, int WM, int WN>
__global__ __launch_bounds__(256) void gemm_k(const bf16_t* __restrict__ A, const bf16_t* __restrict__ Bt,
                                              const float* __restrict__ bias, const float* __restrict__ res,
                                              float* __restrict__ out, int M, int N, int K, int epi) {
  constexpr int BK = 32;
  constexpr int WIN_M = WM / 16, WIN_N = WN / 16;
  __shared__ bf16_t lA[BM * BK];
  __shared__ bf16_t lB[BN * BK];
  const int wave = threadIdx.x >> 6, lane = threadIdx.x & 63;
  const int m0 = blockIdx.y * BM, n0 = blockIdx.x * BN;
  const int wm = wave >> 1, wn = wave & 1;  // 2x2 wave grid (both configs)
  f32x4 acc[WIN_M][WIN_N] = {};
  const int lrow = lane >> 2, lcb = (lane & 3) * 8;
  const int ksub = (lane >> 4) * 8, rsub = lane & 15;
  for (int kt = 0; kt < K; kt += BK) {
    for (int i = wave; i < BM / 16; i += 4)
      async_load16(A + (size_t)(m0 + i * 16 + lrow) * K + kt + lcb, &lA[i * 16 * BK]);
    for (int i = wave; i < BN / 16; i += 4)
      async_load16(Bt + (size_t)(n0 + i * 16 + lrow) * K + kt + lcb, &lB[i * 16 * BK]);
    __syncthreads();
    bf16x8 af[WIN_M], bfr[WIN_N];
#pragma unroll
    for (int mi = 0; mi < WIN_M; ++mi) af[mi] = *(const bf16x8*)&lA[(wm * WM + mi * 16 + rsub) * BK + ksub];
#pragma unroll
    for (int ni = 0; ni < WIN_N; ++ni) bfr[ni] = *(const bf16x8*)&lB[(wn * WN + ni * 16 + rsub) * BK + ksub];
#pragma unroll
    for (int mi = 0; mi < WIN_M; ++mi)
#pragma unroll
      for (int ni = 0; ni < WIN_N; ++ni)
        acc[mi][ni] = __builtin_amdgcn_mfma_f32_16x16x32_bf16(af[mi], bfr[ni], acc[mi][ni], 0, 0, 0);
    __syncthreads();
  }
  // epilogue: D layout col=lane&15, row=(lane>>4)*4+reg (m89-verified)
#pragma unroll
  for (int mi = 0; mi < WIN_M; ++mi)
#pragma unroll
    for (int ni = 0; ni < WIN_N; ++ni) {
      const int col = n0 + wn * WN + ni * 16 + (lane & 15);
      const int row0 = m0 + wm * WM + mi * 16 + (lane >> 4) * 4;
      const float bv = bias ? bias[col] : 0.f;
#pragma unroll
      for (int r = 0; r < 4; ++r) {
        float v = acc[mi][ni][r] + bv;
        v = gelu_f(v);
        if (epi == 2 && (col >> 9) == 1) v *= kSCALE;
        if (epi == 3) v += res[(size_t)(row0 + r) * N + col];
        out[(size_t)(row0 + r) * N + col] = v;
      }
    }
}

// ---------------- theta-shift + head repack: qkvg(f32 rows of 2048) -> qr,kr,vr bf16 (B,H,T,64) ----------------
__global__ __launch_bounds__(256) void theta_k(const float* __restrict__ qkvg, const float* __restrict__ tc,
                                               const float* __restrict__ ts, bf16_t* __restrict__ qr,
                                               bf16_t* __restrict__ kr, bf16_t* __restrict__ vr) {
  typedef __bf16 bf16x2 __attribute__((ext_vector_type(2)));
  const int tid = blockIdx.x * 256 + threadIdx.x;  // 2^20
  const int i = tid & 31, h = (tid >> 5) & 7, t = (tid >> 8) & 2047, b = tid >> 19;
  const size_t srow = ((size_t)(b * Tc + t)) * 2048 + h * 64 + 2 * i;
  const float2 q = *(const float2*)&qkvg[srow];
  const float2 k = *(const float2*)&qkvg[srow + 512];
  const float2 v = *(const float2*)&qkvg[srow + 1024];
  const float c = tc[t * 32 + i], s = ts[t * 32 + i];
  const size_t drow = (((size_t)(b * Hc + h)) * Tc + t) * 64 + 2 * i;
  bf16x2 o;
  o[0] = (bf16_t)(q.x * c - q.y * s); o[1] = (bf16_t)(q.y * c + q.x * s);
  *(bf16x2*)&qr[drow] = o;
  o[0] = (bf16_t)(k.x * c - k.y * s); o[1] = (bf16_t)(k.y * c + k.x * s);
  *(bf16x2*)&kr[drow] = o;
  o[0] = (bf16_t)v.x; o[1] = (bf16_t)v.y;
  *(bf16x2*)&vr[drow] = o;
}

// ---------------- retention: single-pass decay-weighted attention ----------------
// block = (b,h) x 64-row q-tile; 4 waves x 16 rows. Normalization applied at the end:
// out[t] = (Σ_s w·qk·v)·rt / (max(|Σ_s w·qk|·rt,1)+eps), rt = rsqrt(Σ_{j<=t} e^{jd}).
__global__ __launch_bounds__(256) void retention_k(const bf16_t* __restrict__ qr, const bf16_t* __restrict__ kr,
                                                   const bf16_t* __restrict__ vr, float* __restrict__ ao) {
  const int bh = blockIdx.y;
  const int h = bh & 7, b = bh >> 3;
  const int t0 = blockIdx.x * 64;
  const int wave = threadIdx.x >> 6, lane = threadIdx.x & 63;
  const float dec = log1pf(-exp2f(-5.f - (float)h));
  __shared__ bf16_t vT[64][72];        // [d][s] transposed V tile (+pad)
  __shared__ bf16_t sS[4][16][72];     // per-wave masked S tile [t_local][s_local]
  const size_t base = (size_t)bh * Tc * 64;
  const int tw = t0 + wave * 16;
  const int gi = lane >> 4, li = lane & 15;
  bf16x8 qf0, qf1;
  {
    const bf16_t* qp = qr + base + (size_t)(tw + li) * 64 + gi * 8;
    qf0 = *(const bf16x8*)qp;
    qf1 = *(const bf16x8*)(qp + 32);
  }
  f32x4 accv[4] = {};
  float rs[4] = {0.f, 0.f, 0.f, 0.f};
  const int nS = blockIdx.x + 1;
  for (int st = 0; st < nS; ++st) {
    const int s0 = st * 64;
    __syncthreads();  // protect vT from previous iteration's readers
    for (int j = threadIdx.x; j < 64 * 64; j += 256) {
      const int s = j >> 6, dd = j & 63;
      vT[dd][s] = vr[base + (size_t)(s0 + s) * 64 + dd];
    }
    __syncthreads();
    const bf16_t* kb = kr + base + (size_t)s0 * 64;
    float aT[4];
#pragma unroll
    for (int r = 0; r < 4; ++r) aT[r] = expf(dec * (float)(tw + gi * 4 + r - s0));
#pragma unroll
    for (int sc = 0; sc < 4; ++sc) {
      const bf16_t* kp = kb + (size_t)(sc * 16 + li) * 64 + gi * 8;
      const bf16x8 kf0 = *(const bf16x8*)kp;
      const bf16x8 kf1 = *(const bf16x8*)(kp + 32);
      f32x4 Sv = {};
      Sv = __builtin_amdgcn_mfma_f32_16x16x32_bf16(qf0, kf0, Sv, 0, 0, 0);
      Sv = __builtin_amdgcn_mfma_f32_16x16x32_bf16(qf1, kf1, Sv, 0, 0, 0);
      const int s_l = sc * 16 + li;
      const float bSc = expf(-dec * (float)s_l);
#pragma unroll
      for (int r = 0; r < 4; ++r) {
        const int tl = gi * 4 + r;
        const float w = (s0 + s_l <= tw + tl) ? aT[r] * bSc : 0.f;
        const float val = Sv[r] * w;
        rs[r] += val;
        sS[wave][tl][s_l] = (bf16_t)val;
      }
    }
    __syncthreads();  // order sS writes -> A-frag reads (and uniform across waves)
    const bf16x8 pa0 = *(const bf16x8*)&sS[wave][li][gi * 8];
    const bf16x8 pa1 = *(const bf16x8*)&sS[wave][li][32 + gi * 8];
#pragma unroll
    for (int dd = 0; dd < 4; ++dd) {
      const bf16x8 vb0 = *(const bf16x8*)&vT[dd * 16 + li][gi * 8];
      const bf16x8 vb1 = *(const bf16x8*)&vT[dd * 16 + li][32 + gi * 8];
      accv[dd] = __builtin_amdgcn_mfma_f32_16x16x32_bf16(pa0, vb0, accv[dd], 0, 0, 0);
      accv[dd] = __builtin_amdgcn_mfma_f32_16x16x32_bf16(pa1, vb1, accv[dd], 0, 0, 0);
    }
  }
#pragma unroll
  for (int r = 0; r < 4; ++r) {
    float v = rs[r];
    v += __shfl_xor(v, 1); v += __shfl_xor(v, 2); v += __shfl_xor(v, 4); v += __shfl_xor(v, 8);
    rs[r] = v;
  }
  const float inv1md = exp2f(5.f + (float)h);  // 1/(1-e^d) exactly
#pragma unroll
  for (int r = 0; r < 4; ++r) {
    const int t = tw + gi * 4 + r;
    const float Ssum = -expm1f(dec * (float)(t + 1)) * inv1md;
    const float rt = rsqrtf(Ssum);
    const float den = fmaxf(fabsf(rs[r] * rt), 1.0f) + kEPS;
    const float scl = rt / den;
    float* op = ao + ((size_t)(b * Tc + t)) * Cc + h * 64 + li;
#pragma unroll
    for (int dd = 0; dd < 4; ++dd) op[dd * 16] = accv[dd][r] * scl;
  }
}

// ---------------- post-retention: LN(ao) * silu(g) -> bf16 ----------------
__global__ __launch_bounds__(256) void postret_k(const float* __restrict__ ao, const float* __restrict__ qkvg,
                                                 bf16_t* __restrict__ gated) {
  const int row = blockIdx.x;
  const float* rp = ao + (size_t)row * 512;
  float v0 = rp[threadIdx.x], v1 = rp[threadIdx.x + 256];
  float s = v0 + v1, sq = v0 * v0 + v1 * v1;
#pragma unroll
  for (int m = 1; m < 64; m <<= 1) { s += __shfl_xor(s, m); sq += __shfl_xor(sq, m); }
  __shared__ float red[8];
  const int wave = threadIdx.x >> 6, lane = threadIdx.x & 63;
  if (lane == 0) { red[wave] = s; red[4 + wave] = sq; }
  __syncthreads();
  s = red[0] + red[1] + red[2] + red[3];
  sq = red[4] + red[5] + red[6] + red[7];
  const float mean = s * (1.f / 512.f);
  const float inv = rsqrtf(sq * (1.f / 512.f) - mean * mean + kEPS);
  const float* gp = qkvg + (size_t)row * 2048 + 1536;
  const float g0 = gp[threadIdx.x], g1 = gp[threadIdx.x + 256];
  bf16_t* op = gated + (size_t)row * 512;
  op[threadIdx.x] = (bf16_t)(g0 / (1.f + expf(-g0)) * (v0 - mean) * inv);
  op[threadIdx.x + 256] = (bf16_t)(g1 / (1.f + expf(-g1)) * (v1 - mean) * inv);
}

extern "C" void kernel_launch(void* const* d_in, const int* in_sizes, int n_in,
                              void* d_out, int out_size, void* d_ws, size_t ws_size,
                              hipStream_t stream) {
  const float* x_in = (const float*)d_in[0];
  const float* Wq = (const float*)d_in[1];
  const float* bq = (const float*)d_in[2];
  const float* Wk = (const float*)d_in[3];
  const float* bk = (const float*)d_in[4];
  const float* Wv = (const float*)d_in[5];
  const float* bv = (const float*)d_in[6];
  const float* Wg = (const float*)d_in[7];
  const float* bg = (const float*)d_in[8];
  const float* Wo = (const float*)d_in[9];
  const float* bo = (const float*)d_in[10];
  const float* W1 = (const float*)d_in[11];
  const float* b1 = (const float*)d_in[12];
  const float* W2 = (const float*)d_in[13];
  const float* b2 = (const float*)d_in[14];

  char* ws = (char*)d_ws;
  bf16_t* WQKVG = (bf16_t*)(ws + OFF_WQKVG);
  bf16_t* WOt   = (bf16_t*)(ws + OFF_WO);
  bf16_t* W1t   = (bf16_t*)(ws + OFF_W1);
  bf16_t* W2t   = (bf16_t*)(ws + OFF_W2);
  float*  BQKVG = (float*)(ws + OFF_BQKVG);
  float*  TABC  = (float*)(ws + OFF_TABC);
  float*  TABS  = (float*)(ws + OFF_TABS);
  bf16_t* HLN   = (bf16_t*)(ws + OFF_HLN);
  float*  QKVG  = (float*)(ws + OFF_QKVG);
  bf16_t* QR    = (bf16_t*)(ws + OFF_QR);
  bf16_t* KR    = (bf16_t*)(ws + OFF_KR);
  bf16_t* VR    = (bf16_t*)(ws + OFF_VR);
  float*  AO    = (float*)(ws + OFF_AO);
  bf16_t* GATED = (bf16_t*)(ws + OFF_GATED);
  float*  xbuf  = (float*)d_out;  // x accumulates in-place in d_out

  hipMemcpyAsync(xbuf, x_in, (size_t)Mc * Cc * 4, hipMemcpyDeviceToDevice, stream);

  // ---- prep (every launch; graph-consistent) ----
  const dim3 tb(32, 8);
  const float* wsrc[4] = {Wq, Wk, Wv, Wg};
  for (int c = 0; c < 4; ++c)
    transpose_pack_k<<<dim3(Cc / 32, Cc / 32, Lc), tb, 0, stream>>>(
        wsrc[c], WQKVG + (size_t)c * Cc * Cc, Cc, Cc, (size_t)Cc * Cc, (size_t)2048 * Cc);
  transpose_pack_k<<<dim3(Cc / 32, Cc / 32, Lc), tb, 0, stream>>>(
      Wo, WOt, Cc, Cc, (size_t)Cc * Cc, (size_t)Cc * Cc);
  transpose_pack_k<<<dim3(FFNc / 32, Cc / 32, Lc), tb, 0, stream>>>(
      W1, W1t, Cc, FFNc, (size_t)Cc * FFNc, (size_t)FFNc * Cc);
  transpose_pack_k<<<dim3(Cc / 32, FFNc / 32, Lc), tb, 0, stream>>>(
      W2, W2t, FFNc, Cc, (size_t)FFNc * Cc, (size_t)Cc * FFNc);
  biaspack_k<<<32, 256, 0, stream>>>(bq, bk, bv, bg, BQKVG);
  trig_k<<<256, 256, 0, stream>>>(TABC, TABS);

  for (int l = 0; l < Lc; ++l) {
    // retention block
    ln_k<512><<<Mc, 256, 0, stream>>>(xbuf, HLN);
    gemm_k<128, 128, 64, 64><<<dim3(2048 / 128, Mc / 128), 256, 0, stream>>>(
        HLN, WQKVG + (size_t)l * 2048 * 512, BQKVG + l * 2048, nullptr, QKVG, Mc, 2048, 512, 2);
    theta_k<<<(1 << 20) / 256, 256, 0, stream>>>(QKVG, TABC, TABS, QR, KR, VR);
    retention_k<<<dim3(Tc / 64, Bc * Hc), 256, 0, stream>>>(QR, KR, VR, AO);
    postret_k<<<Mc, 256, 0, stream>>>(AO, QKVG, GATED);
    gemm_k<128, 64, 64, 32><<<dim3(512 / 64, Mc / 128), 256, 0, stream>>>(
        GATED, WOt + (size_t)l * 512 * 512, bo + l * 512, xbuf, xbuf, Mc, 512, 512, 3);
    // FFN block
    ln_k<512><<<Mc, 256, 0, stream>>>(xbuf, HLN);
    gemm_k<128, 128, 64, 64><<<dim3(2048 / 128, Mc / 128), 256, 0, stream>>>(
        HLN, W1t + (size_t)l * 2048 * 512, b1 + l * 2048, nullptr, QKVG, Mc, 2048, 512, 1);
    ln_k<2048><<<Mc, 256, 0, stream>>>(QKVG, HLN);
    gemm_k<128, 64, 64, 32><<<dim3(512 / 64, Mc / 128), 256, 0, stream>>>(
        HLN, W2t + (size_t)l * 512 * 2048, b2 + l * 512, xbuf, xbuf, Mc, 512, 2048, 3);
  }
}

// Round 2
// 1308.802 us; speedup vs baseline: 1.2182x; 1.2182x over previous
//
#include <hip/hip_runtime.h>
#include <math.h>

typedef __bf16 bf16_t;
typedef __bf16 bf16x8 __attribute__((ext_vector_type(8)));
typedef float f32x4 __attribute__((ext_vector_type(4)));

#define DEV __device__ __forceinline__

constexpr int Bc = 2, Tc = 2048, Cc = 512, Hc = 8, FFNc = 2048, Lc = 4;
constexpr int Mc = Bc * Tc;           // 4096 rows
constexpr float kSCALE = 0.125f;      // KD^-0.5, KD=64
constexpr float kEPS = 1e-6f;

// ---------------- workspace layout (bytes) ----------------
constexpr size_t OFF_WQKVG = 0;                                    // L*2048*512 bf16
constexpr size_t OFF_WO    = OFF_WQKVG + (size_t)Lc*2048*512*2;    // L*512*512 bf16
constexpr size_t OFF_W1    = OFF_WO    + (size_t)Lc*512*512*2;     // L*2048*512 bf16
constexpr size_t OFF_W2    = OFF_W1    + (size_t)Lc*2048*512*2;    // L*512*2048 bf16
constexpr size_t OFF_BQKVG = OFF_W2    + (size_t)Lc*512*2048*2;    // L*2048 f32
constexpr size_t OFF_TABC  = OFF_BQKVG + (size_t)Lc*2048*4;        // 2048*32 f32
constexpr size_t OFF_TABS  = OFF_TABC  + (size_t)Tc*32*4;
constexpr size_t OFF_HLN   = OFF_TABS  + (size_t)Tc*32*4;          // 4096*2048 bf16
constexpr size_t OFF_QKVG  = OFF_HLN   + (size_t)Mc*2048*2;        // 4096*2048 f32
constexpr size_t OFF_QR    = OFF_QKVG  + (size_t)Mc*2048*4;        // (B,H,T,64) bf16
constexpr size_t OFF_KR    = OFF_QR    + (size_t)Bc*Hc*Tc*64*2;
constexpr size_t OFF_VT    = OFF_KR    + (size_t)Bc*Hc*Tc*64*2;    // (B,H,64,T) bf16 transposed V
constexpr size_t OFF_AO    = OFF_VT    + (size_t)Bc*Hc*64*Tc*2;    // 4096*512 f32 raw retention sums
constexpr size_t OFF_RS    = OFF_AO    + (size_t)Mc*512*4;         // B*H*T f32 raw row sums
constexpr size_t OFF_GATED = OFF_RS    + (size_t)Bc*Hc*Tc*4;       // 4096*512 bf16
// total ~99 MB

DEV float gelu_f(float x) { return 0.5f * x * (1.0f + erff(x * 0.70710678118654752f)); }

DEV void async_load16(const void* g, void* l) {
  __builtin_amdgcn_global_load_lds((const __attribute__((address_space(1))) unsigned int*)g,
                                   (__attribute__((address_space(3))) unsigned int*)l, 16, 0, 0);
}

// ---------------- weight transpose+pack: dst[n*K+k] = bf16(src[k*N+n]) ----------------
__global__ __launch_bounds__(256) void transpose_pack_k(const float* __restrict__ src, bf16_t* __restrict__ dst,
                                                        int K, int N, size_t src_lstride, size_t dst_lstride) {
  __shared__ float tile[32][33];
  src += blockIdx.z * src_lstride;
  dst += blockIdx.z * dst_lstride;
  const int n0 = blockIdx.x * 32, k0 = blockIdx.y * 32;
  const int tx = threadIdx.x, ty = threadIdx.y;  // (32,8)
#pragma unroll
  for (int j = 0; j < 32; j += 8) tile[ty + j][tx] = src[(size_t)(k0 + ty + j) * N + n0 + tx];
  __syncthreads();
#pragma unroll
  for (int j = 0; j < 32; j += 8) dst[(size_t)(n0 + ty + j) * K + k0 + tx] = (bf16_t)tile[tx][ty + j];
}

__global__ __launch_bounds__(256) void biaspack_k(const float* __restrict__ bq, const float* __restrict__ bk,
                                                  const float* __restrict__ bv, const float* __restrict__ bg,
                                                  float* __restrict__ outp) {
  const int tid = blockIdx.x * 256 + threadIdx.x;  // L*2048
  const int l = tid >> 11, n = tid & 2047;
  const float* srcs[4] = {bq, bk, bv, bg};
  outp[tid] = srcs[n >> 9][l * 512 + (n & 511)];
}

__global__ __launch_bounds__(256) void trig_k(float* __restrict__ tc, float* __restrict__ ts) {
  const int tid = blockIdx.x * 256 + threadIdx.x;  // 65536
  const int t = tid >> 5, i = tid & 31;
  const float angle = powf(10000.f, -(float)i / 31.f);
  const float a = (float)t * angle;
  tc[tid] = cosf(a);
  ts[tid] = sinf(a);
}

// ---------------- LayerNorm (no affine) fp32 in -> bf16 out ----------------
template <int NC>
__global__ __launch_bounds__(256) void ln_k(const float* __restrict__ in, bf16_t* __restrict__ out) {
  constexpr int PT = NC / 256;
  const int row = blockIdx.x;
  const float* rp = in + (size_t)row * NC;
  float v[PT], s = 0.f, sq = 0.f;
#pragma unroll
  for (int i = 0; i < PT; ++i) { v[i] = rp[threadIdx.x + i * 256]; s += v[i]; sq += v[i] * v[i]; }
#pragma unroll
  for (int m = 1; m < 64; m <<= 1) { s += __shfl_xor(s, m); sq += __shfl_xor(sq, m); }
  __shared__ float red[8];
  const int wave = threadIdx.x >> 6, lane = threadIdx.x & 63;
  if (lane == 0) { red[wave] = s; red[4 + wave] = sq; }
  __syncthreads();
  s = red[0] + red[1] + red[2] + red[3];
  sq = red[4] + red[5] + red[6] + red[7];
  const float mean = s * (1.f / NC);
  const float inv = rsqrtf(sq * (1.f / NC) - mean * mean + kEPS);
  bf16_t* op = out + (size_t)row * NC;
#pragma unroll
  for (int i = 0; i < PT; ++i) op[threadIdx.x + i * 256] = (bf16_t)((v[i] - mean) * inv);
}

// ---------------- GEMM: out(f32) = epi(A(bf16, MxK) @ Bt(bf16, NxK)^T + bias) ----------------
template <int BM, int BN, int WM, int WN>
__global__ __launch_bounds__(256) void gemm_k(const bf16_t* __restrict__ A, const bf16_t* __restrict__ Bt,
                                              const float* __restrict__ bias, const float* __restrict__ res,
                                              float* __restrict__ out, int M, int N, int K, int epi) {
  constexpr int BK = 32;
  constexpr int WIN_M = WM / 16, WIN_N = WN / 16;
  __shared__ bf16_t lA[BM * BK];
  __shared__ bf16_t lB[BN * BK];
  const int wave = threadIdx.x >> 6, lane = threadIdx.x & 63;
  const int m0 = blockIdx.y * BM, n0 = blockIdx.x * BN;
  const int wm = wave >> 1, wn = wave & 1;
  f32x4 acc[WIN_M][WIN_N] = {};
  const int lrow = lane >> 2, lcb = (lane & 3) * 8;
  const int ksub = (lane >> 4) * 8, rsub = lane & 15;
  for (int kt = 0; kt < K; kt += BK) {
    for (int i = wave; i < BM / 16; i += 4)
      async_load16(A + (size_t)(m0 + i * 16 + lrow) * K + kt + lcb, &lA[i * 16 * BK]);
    for (int i = wave; i < BN / 16; i += 4)
      async_load16(Bt + (size_t)(n0 + i * 16 + lrow) * K + kt + lcb, &lB[i * 16 * BK]);
    __syncthreads();
    bf16x8 af[WIN_M], bfr[WIN_N];
#pragma unroll
    for (int mi = 0; mi < WIN_M; ++mi) af[mi] = *(const bf16x8*)&lA[(wm * WM + mi * 16 + rsub) * BK + ksub];
#pragma unroll
    for (int ni = 0; ni < WIN_N; ++ni) bfr[ni] = *(const bf16x8*)&lB[(wn * WN + ni * 16 + rsub) * BK + ksub];
#pragma unroll
    for (int mi = 0; mi < WIN_M; ++mi)
#pragma unroll
      for (int ni = 0; ni < WIN_N; ++ni)
        acc[mi][ni] = __builtin_amdgcn_mfma_f32_16x16x32_bf16(af[mi], bfr[ni], acc[mi][ni], 0, 0, 0);
    __syncthreads();
  }
#pragma unroll
  for (int mi = 0; mi < WIN_M; ++mi)
#pragma unroll
    for (int ni = 0; ni < WIN_N; ++ni) {
      const int col = n0 + wn * WN + ni * 16 + (lane & 15);
      const int row0 = m0 + wm * WM + mi * 16 + (lane >> 4) * 4;
      const float bv = bias ? bias[col] : 0.f;
#pragma unroll
      for (int r = 0; r < 4; ++r) {
        float v = acc[mi][ni][r] + bv;
        v = gelu_f(v);
        if (epi == 2 && (col >> 9) == 1) v *= kSCALE;
        if (epi == 3) v += res[(size_t)(row0 + r) * N + col];
        out[(size_t)(row0 + r) * N + col] = v;
      }
    }
}

// ---------------- theta-shift + head repack: qkvg -> qr,kr bf16 (B,H,T,64) ----------------
__global__ __launch_bounds__(256) void theta_k(const float* __restrict__ qkvg, const float* __restrict__ tc,
                                               const float* __restrict__ ts, bf16_t* __restrict__ qr,
                                               bf16_t* __restrict__ kr) {
  typedef __bf16 bf16x2 __attribute__((ext_vector_type(2)));
  const int tid = blockIdx.x * 256 + threadIdx.x;  // 2^20
  const int i = tid & 31, h = (tid >> 5) & 7, t = (tid >> 8) & 2047, b = tid >> 19;
  const size_t srow = ((size_t)(b * Tc + t)) * 2048 + h * 64 + 2 * i;
  const float2 q = *(const float2*)&qkvg[srow];
  const float2 k = *(const float2*)&qkvg[srow + 512];
  const float c = tc[t * 32 + i], s = ts[t * 32 + i];
  const size_t drow = (((size_t)(b * Hc + h)) * Tc + t) * 64 + 2 * i;
  bf16x2 o;
  o[0] = (bf16_t)(q.x * c - q.y * s); o[1] = (bf16_t)(q.y * c + q.x * s);
  *(bf16x2*)&qr[drow] = o;
  o[0] = (bf16_t)(k.x * c - k.y * s); o[1] = (bf16_t)(k.y * c + k.x * s);
  *(bf16x2*)&kr[drow] = o;
}

// ---------------- V transpose: qkvg v-slice (f32) -> VT[bh][d][t] (bf16) ----------------
__global__ __launch_bounds__(256) void vtrans_k(const float* __restrict__ qkvg, bf16_t* __restrict__ vt) {
  const int bh = blockIdx.y, t0 = blockIdx.x * 64;
  const int b = bh >> 3, h = bh & 7;
#pragma unroll
  for (int it = 0; it < 2; ++it) {
    const int idx = it * 256 + threadIdx.x;
    const int d = idx >> 3, tc8 = (idx & 7) * 8;
    const float* src = qkvg + (size_t)(b * Tc + t0 + tc8) * 2048 + 1024 + h * 64 + d;
    bf16x8 o;
#pragma unroll
    for (int k = 0; k < 8; ++k) o[k] = (bf16_t)src[(size_t)k * 2048];
    *(bf16x8*)&vt[(size_t)(bh * 64 + d) * Tc + t0 + tc8] = o;
  }
}

// ---------------- retention: split-K decay-weighted attention, partials via atomics ----------------
// grid (qtile=32, bh=16, slice=4); 4 waves x 16 q-rows; no __syncthreads (sS is per-wave).
__global__ __launch_bounds__(256) void retention_k(const bf16_t* __restrict__ qr, const bf16_t* __restrict__ kr,
                                                   const bf16_t* __restrict__ vt, float* __restrict__ aop,
                                                   float* __restrict__ rsp) {
  const int q = blockIdx.x, bh = blockIdx.y, sl = blockIdx.z;
  const int ntiles = q + 1;
  const int lo = (ntiles * sl) >> 2, hi = (ntiles * (sl + 1)) >> 2;
  if (hi <= lo) return;
  const int h = bh & 7, b = bh >> 3;
  const int wave = threadIdx.x >> 6, lane = threadIdx.x & 63;
  const int gi = lane >> 4, li = lane & 15;
  const float dec = log1pf(-exp2f(-5.f - (float)h));
  const float d2 = dec * 1.44269504088896340736f;
  __shared__ bf16_t sS[4][16][76];  // per-wave P tile [t_local][s_local], stride 76 (bank-disjoint)
  const size_t base = (size_t)bh * Tc * 64;
  const int tw = q * 64 + wave * 16;
  bf16x8 qf0, qf1;
  {
    const bf16_t* qp = qr + base + (size_t)(tw + li) * 64 + gi * 8;
    qf0 = *(const bf16x8*)qp;
    qf1 = *(const bf16x8*)(qp + 32);
  }
  float bS[4];
#pragma unroll
  for (int sc = 0; sc < 4; ++sc) bS[sc] = exp2f(-d2 * (float)(sc * 16 + li));
  f32x4 accv[4] = {};
  float rs[4] = {0.f, 0.f, 0.f, 0.f};
  for (int st = lo; st < hi; ++st) {
    const int s0 = st * 64;
    const bf16_t* kb = kr + base + (size_t)s0 * 64;
    float aT[4];
#pragma unroll
    for (int r = 0; r < 4; ++r) aT[r] = exp2f(d2 * (float)(tw + gi * 4 + r - s0));
#pragma unroll
    for (int sc = 0; sc < 4; ++sc) {
      const bf16_t* kp = kb + (size_t)(sc * 16 + li) * 64 + gi * 8;
      const bf16x8 kf0 = *(const bf16x8*)kp;
      const bf16x8 kf1 = *(const bf16x8*)(kp + 32);
      f32x4 Sv = {};
      Sv = __builtin_amdgcn_mfma_f32_16x16x32_bf16(qf0, kf0, Sv, 0, 0, 0);
      Sv = __builtin_amdgcn_mfma_f32_16x16x32_bf16(qf1, kf1, Sv, 0, 0, 0);
      const int s_l = sc * 16 + li;
#pragma unroll
      for (int r = 0; r < 4; ++r) {
        const int tl = gi * 4 + r;
        const float w = (s0 + s_l <= tw + tl) ? aT[r] * bS[sc] : 0.f;
        const float val = Sv[r] * w;
        rs[r] += val;
        sS[wave][tl][s_l] = (bf16_t)val;
      }
    }
    const bf16x8 pa0 = *(const bf16x8*)&sS[wave][li][gi * 8];
    const bf16x8 pa1 = *(const bf16x8*)&sS[wave][li][32 + gi * 8];
#pragma unroll
    for (int dd = 0; dd < 4; ++dd) {
      const bf16_t* vrow = vt + (size_t)(bh * 64 + dd * 16 + li) * Tc + s0;
      const bf16x8 vb0 = *(const bf16x8*)(vrow + gi * 8);
      const bf16x8 vb1 = *(const bf16x8*)(vrow + 32 + gi * 8);
      accv[dd] = __builtin_amdgcn_mfma_f32_16x16x32_bf16(pa0, vb0, accv[dd], 0, 0, 0);
      accv[dd] = __builtin_amdgcn_mfma_f32_16x16x32_bf16(pa1, vb1, accv[dd], 0, 0, 0);
    }
  }
  // reduce row-sum partials over li (bits 1,2,4,8 stay within the 16-lane group)
#pragma unroll
  for (int r = 0; r < 4; ++r) {
    float v = rs[r];
    v += __shfl_xor(v, 1); v += __shfl_xor(v, 2); v += __shfl_xor(v, 4); v += __shfl_xor(v, 8);
    rs[r] = v;
  }
#pragma unroll
  for (int r = 0; r < 4; ++r) {
    const int t = tw + gi * 4 + r;
    if (li == 0) atomicAdd(&rsp[(size_t)bh * Tc + t], rs[r]);
    float* op = aop + ((size_t)(b * Tc + t)) * Cc + h * 64 + li;
#pragma unroll
    for (int dd = 0; dd < 4; ++dd) atomicAdd(&op[dd * 16], accv[dd][r]);
  }
}

// ---------------- post-retention: normalize + LN + silu(g) gate -> bf16 ----------------
__global__ __launch_bounds__(256) void postret_k(const float* __restrict__ ao, const float* __restrict__ qkvg,
                                                 const float* __restrict__ rsp, bf16_t* __restrict__ gated) {
  const int row = blockIdx.x;
  const int b = row >> 11, t = row & 2047;
  const float* rp = ao + (size_t)row * 512;
  float v[2];
#pragma unroll
  for (int i = 0; i < 2; ++i) {
    const int c = threadIdx.x + i * 256;
    const int h = c >> 6;
    const float dec_h = log1pf(-exp2f(-5.f - (float)h));
    const float Ssum = -expm1f(dec_h * (float)(t + 1)) * exp2f(5.f + (float)h);
    const float rt = rsqrtf(Ssum);
    const float rsv = rsp[(size_t)(b * 8 + h) * Tc + t];
    const float den = fmaxf(fabsf(rsv * rt), 1.0f) + kEPS;
    v[i] = rp[c] * (rt / den);
  }
  float s = v[0] + v[1], sq = v[0] * v[0] + v[1] * v[1];
#pragma unroll
  for (int m = 1; m < 64; m <<= 1) { s += __shfl_xor(s, m); sq += __shfl_xor(sq, m); }
  __shared__ float red[8];
  const int wave = threadIdx.x >> 6, lane = threadIdx.x & 63;
  if (lane == 0) { red[wave] = s; red[4 + wave] = sq; }
  __syncthreads();
  s = red[0] + red[1] + red[2] + red[3];
  sq = red[4] + red[5] + red[6] + red[7];
  const float mean = s * (1.f / 512.f);
  const float inv = rsqrtf(sq * (1.f / 512.f) - mean * mean + kEPS);
  const float* gp = qkvg + (size_t)row * 2048 + 1536;
  bf16_t* op = gated + (size_t)row * 512;
#pragma unroll
  for (int i = 0; i < 2; ++i) {
    const int c = threadIdx.x + i * 256;
    const float g = gp[c];
    op[c] = (bf16_t)(g / (1.f + expf(-g)) * (v[i] - mean) * inv);
  }
}

extern "C" void kernel_launch(void* const* d_in, const int* in_sizes, int n_in,
                              void* d_out, int out_size, void* d_ws, size_t ws_size,
                              hipStream_t stream) {
  const float* x_in = (const float*)d_in[0];
  const float* Wq = (const float*)d_in[1];
  const float* bq = (const float*)d_in[2];
  const float* Wk = (const float*)d_in[3];
  const float* bk = (const float*)d_in[4];
  const float* Wv = (const float*)d_in[5];
  const float* bv = (const float*)d_in[6];
  const float* Wg = (const float*)d_in[7];
  const float* bg = (const float*)d_in[8];
  const float* Wo = (const float*)d_in[9];
  const float* bo = (const float*)d_in[10];
  const float* W1 = (const float*)d_in[11];
  const float* b1 = (const float*)d_in[12];
  const float* W2 = (const float*)d_in[13];
  const float* b2 = (const float*)d_in[14];

  char* ws = (char*)d_ws;
  bf16_t* WQKVG = (bf16_t*)(ws + OFF_WQKVG);
  bf16_t* WOt   = (bf16_t*)(ws + OFF_WO);
  bf16_t* W1t   = (bf16_t*)(ws + OFF_W1);
  bf16_t* W2t   = (bf16_t*)(ws + OFF_W2);
  float*  BQKVG = (float*)(ws + OFF_BQKVG);
  float*  TABC  = (float*)(ws + OFF_TABC);
  float*  TABS  = (float*)(ws + OFF_TABS);
  bf16_t* HLN   = (bf16_t*)(ws + OFF_HLN);
  float*  QKVG  = (float*)(ws + OFF_QKVG);
  bf16_t* QR    = (bf16_t*)(ws + OFF_QR);
  bf16_t* KR    = (bf16_t*)(ws + OFF_KR);
  bf16_t* VT    = (bf16_t*)(ws + OFF_VT);
  float*  AO    = (float*)(ws + OFF_AO);
  float*  RS    = (float*)(ws + OFF_RS);
  bf16_t* GATED = (bf16_t*)(ws + OFF_GATED);
  float*  xbuf  = (float*)d_out;

  hipMemcpyAsync(xbuf, x_in, (size_t)Mc * Cc * 4, hipMemcpyDeviceToDevice, stream);

  // ---- prep ----
  const dim3 tb(32, 8);
  const float* wsrc[4] = {Wq, Wk, Wv, Wg};
  for (int c = 0; c < 4; ++c)
    transpose_pack_k<<<dim3(Cc / 32, Cc / 32, Lc), tb, 0, stream>>>(
        wsrc[c], WQKVG + (size_t)c * Cc * Cc, Cc, Cc, (size_t)Cc * Cc, (size_t)2048 * Cc);
  transpose_pack_k<<<dim3(Cc / 32, Cc / 32, Lc), tb, 0, stream>>>(
      Wo, WOt, Cc, Cc, (size_t)Cc * Cc, (size_t)Cc * Cc);
  transpose_pack_k<<<dim3(FFNc / 32, Cc / 32, Lc), tb, 0, stream>>>(
      W1, W1t, Cc, FFNc, (size_t)Cc * FFNc, (size_t)FFNc * Cc);
  transpose_pack_k<<<dim3(Cc / 32, FFNc / 32, Lc), tb, 0, stream>>>(
      W2, W2t, FFNc, Cc, (size_t)FFNc * Cc, (size_t)Cc * FFNc);
  biaspack_k<<<32, 256, 0, stream>>>(bq, bk, bv, bg, BQKVG);
  trig_k<<<256, 256, 0, stream>>>(TABC, TABS);

  for (int l = 0; l < Lc; ++l) {
    // retention block
    ln_k<512><<<Mc, 256, 0, stream>>>(xbuf, HLN);
    gemm_k<128, 128, 64, 64><<<dim3(2048 / 128, Mc / 128), 256, 0, stream>>>(
        HLN, WQKVG + (size_t)l * 2048 * 512, BQKVG + l * 2048, nullptr, QKVG, Mc, 2048, 512, 2);
    theta_k<<<(1 << 20) / 256, 256, 0, stream>>>(QKVG, TABC, TABS, QR, KR);
    vtrans_k<<<dim3(Tc / 64, Bc * Hc), 256, 0, stream>>>(QKVG, VT);
    hipMemsetAsync(AO, 0, (size_t)Mc * Cc * 4, stream);
    hipMemsetAsync(RS, 0, (size_t)Bc * Hc * Tc * 4, stream);
    retention_k<<<dim3(Tc / 64, Bc * Hc, 4), 256, 0, stream>>>(QR, KR, VT, AO, RS);
    postret_k<<<Mc, 256, 0, stream>>>(AO, QKVG, RS, GATED);
    gemm_k<128, 64, 64, 32><<<dim3(512 / 64, Mc / 128), 256, 0, stream>>>(
        GATED, WOt + (size_t)l * 512 * 512, bo + l * 512, xbuf, xbuf, Mc, 512, 512, 3);
    // FFN block
    ln_k<512><<<Mc, 256, 0, stream>>>(xbuf, HLN);
    gemm_k<128, 128, 64, 64><<<dim3(2048 / 128, Mc / 128), 256, 0, stream>>>(
        HLN, W1t + (size_t)l * 2048 * 512, b1 + l * 2048, nullptr, QKVG, Mc, 2048, 512, 1);
    ln_k<2048><<<Mc, 256, 0, stream>>>(QKVG, HLN);
    gemm_k<128, 64, 64, 32><<<dim3(512 / 64, Mc / 128), 256, 0, stream>>>(
        HLN, W2t + (size_t)l * 512 * 2048, b2 + l * 512, xbuf, xbuf, Mc, 512, 2048, 3);
  }
}

// Round 4
// 1066.473 us; speedup vs baseline: 1.4950x; 1.2272x over previous
//
#include <hip/hip_runtime.h>
#include <math.h>

typedef __bf16 bf16_t;
typedef __bf16 bf16x8 __attribute__((ext_vector_type(8)));
typedef float f32x4 __attribute__((ext_vector_type(4)));

#define DEV __device__ __forceinline__

constexpr int Bc = 2, Tc = 2048, Cc = 512, Hc = 8, FFNc = 2048, Lc = 4;
constexpr int Mc = Bc * Tc;           // 4096 rows
constexpr float kSCALE = 0.125f;      // KD^-0.5, KD=64
constexpr float kEPS = 1e-6f;

// ---------------- workspace layout (bytes) ----------------
constexpr size_t OFF_WQKVG = 0;                                    // L*2048*512 bf16
constexpr size_t OFF_WO    = OFF_WQKVG + (size_t)Lc*2048*512*2;    // L*512*512 bf16
constexpr size_t OFF_W1    = OFF_WO    + (size_t)Lc*512*512*2;     // L*2048*512 bf16
constexpr size_t OFF_W2    = OFF_W1    + (size_t)Lc*2048*512*2;    // L*512*2048 bf16
constexpr size_t OFF_BQKVG = OFF_W2    + (size_t)Lc*512*2048*2;    // L*2048 f32
constexpr size_t OFF_TABC  = OFF_BQKVG + (size_t)Lc*2048*4;        // 2048*32 f32
constexpr size_t OFF_TABS  = OFF_TABC  + (size_t)Tc*32*4;
constexpr size_t OFF_HLN   = OFF_TABS  + (size_t)Tc*32*4;          // 4096*2048 bf16
constexpr size_t OFF_QKVG  = OFF_HLN   + (size_t)Mc*2048*2;        // 4096*2048 f32
constexpr size_t OFF_QR    = OFF_QKVG  + (size_t)Mc*2048*4;        // (B,H,T,64) bf16
constexpr size_t OFF_KR    = OFF_QR    + (size_t)Bc*Hc*Tc*64*2;
constexpr size_t OFF_VT    = OFF_KR    + (size_t)Bc*Hc*Tc*64*2;    // (B,H,64,T) bf16 transposed V
constexpr size_t OFF_AO    = OFF_VT    + (size_t)Bc*Hc*64*Tc*2;    // 4096*512 f32 normalized retention out
constexpr size_t OFF_GATED = OFF_AO    + (size_t)Mc*512*4;         // 4096*512 bf16

DEV float gelu_f(float x) { return 0.5f * x * (1.0f + erff(x * 0.70710678118654752f)); }

DEV void async_load16(const void* g, void* l) {
  __builtin_amdgcn_global_load_lds((const __attribute__((address_space(1))) unsigned int*)g,
                                   (__attribute__((address_space(3))) unsigned int*)l, 16, 0, 0);
}

// ---------------- weight transpose+pack: dst[n*K+k] = bf16(src[k*N+n]) ----------------
__global__ __launch_bounds__(256) void transpose_pack_k(const float* __restrict__ src, bf16_t* __restrict__ dst,
                                                        int K, int N, size_t src_lstride, size_t dst_lstride) {
  __shared__ float tile[32][33];
  src += blockIdx.z * src_lstride;
  dst += blockIdx.z * dst_lstride;
  const int n0 = blockIdx.x * 32, k0 = blockIdx.y * 32;
  const int tx = threadIdx.x, ty = threadIdx.y;  // (32,8)
#pragma unroll
  for (int j = 0; j < 32; j += 8) tile[ty + j][tx] = src[(size_t)(k0 + ty + j) * N + n0 + tx];
  __syncthreads();
#pragma unroll
  for (int j = 0; j < 32; j += 8) dst[(size_t)(n0 + ty + j) * K + k0 + tx] = (bf16_t)tile[tx][ty + j];
}

__global__ __launch_bounds__(256) void biaspack_k(const float* __restrict__ bq, const float* __restrict__ bk,
                                                  const float* __restrict__ bv, const float* __restrict__ bg,
                                                  float* __restrict__ outp) {
  const int tid = blockIdx.x * 256 + threadIdx.x;  // L*2048
  const int l = tid >> 11, n = tid & 2047;
  const float* srcs[4] = {bq, bk, bv, bg};
  outp[tid] = srcs[n >> 9][l * 512 + (n & 511)];
}

__global__ __launch_bounds__(256) void trig_k(float* __restrict__ tc, float* __restrict__ ts) {
  const int tid = blockIdx.x * 256 + threadIdx.x;  // 65536
  const int t = tid >> 5, i = tid & 31;
  const float angle = powf(10000.f, -(float)i / 31.f);
  const float a = (float)t * angle;
  tc[tid] = cosf(a);
  ts[tid] = sinf(a);
}

// ---------------- LayerNorm (no affine) fp32 in -> bf16 out ----------------
template <int NC>
__global__ __launch_bounds__(256) void ln_k(const float* __restrict__ in, bf16_t* __restrict__ out) {
  constexpr int PT = NC / 256;
  const int row = blockIdx.x;
  const float* rp = in + (size_t)row * NC;
  float v[PT], s = 0.f, sq = 0.f;
#pragma unroll
  for (int i = 0; i < PT; ++i) { v[i] = rp[threadIdx.x + i * 256]; s += v[i]; sq += v[i] * v[i]; }
#pragma unroll
  for (int m = 1; m < 64; m <<= 1) { s += __shfl_xor(s, m); sq += __shfl_xor(sq, m); }
  __shared__ float red[8];
  const int wave = threadIdx.x >> 6, lane = threadIdx.x & 63;
  if (lane == 0) { red[wave] = s; red[4 + wave] = sq; }
  __syncthreads();
  s = red[0] + red[1] + red[2] + red[3];
  sq = red[4] + red[5] + red[6] + red[7];
  const float mean = s * (1.f / NC);
  const float inv = rsqrtf(sq * (1.f / NC) - mean * mean + kEPS);
  bf16_t* op = out + (size_t)row * NC;
#pragma unroll
  for (int i = 0; i < PT; ++i) op[threadIdx.x + i * 256] = (bf16_t)((v[i] - mean) * inv);
}

// ---------------- GEMM: out(f32) = epi(A(bf16, MxK) @ Bt(bf16, NxK)^T + bias) ----------------
template <int BM, int BN, int WM, int WN>
__global__ __launch_bounds__(256) void gemm_k(const bf16_t* __restrict__ A, const bf16_t* __restrict__ Bt,
                                              const float* __restrict__ bias, const float* __restrict__ res,
                                              float* __restrict__ out, int M, int N, int K, int epi) {
  constexpr int BK = 32;
  constexpr int WIN_M = WM / 16, WIN_N = WN / 16;
  __shared__ bf16_t lA[BM * BK];
  __shared__ bf16_t lB[BN * BK];
  const int wave = threadIdx.x >> 6, lane = threadIdx.x & 63;
  const int m0 = blockIdx.y * BM, n0 = blockIdx.x * BN;
  const int wm = wave >> 1, wn = wave & 1;
  f32x4 acc[WIN_M][WIN_N] = {};
  const int lrow = lane >> 2, lcb = (lane & 3) * 8;
  const int ksub = (lane >> 4) * 8, rsub = lane & 15;
  for (int kt = 0; kt < K; kt += BK) {
    for (int i = wave; i < BM / 16; i += 4)
      async_load16(A + (size_t)(m0 + i * 16 + lrow) * K + kt + lcb, &lA[i * 16 * BK]);
    for (int i = wave; i < BN / 16; i += 4)
      async_load16(Bt + (size_t)(n0 + i * 16 + lrow) * K + kt + lcb, &lB[i * 16 * BK]);
    __syncthreads();
    bf16x8 af[WIN_M], bfr[WIN_N];
#pragma unroll
    for (int mi = 0; mi < WIN_M; ++mi) af[mi] = *(const bf16x8*)&lA[(wm * WM + mi * 16 + rsub) * BK + ksub];
#pragma unroll
    for (int ni = 0; ni < WIN_N; ++ni) bfr[ni] = *(const bf16x8*)&lB[(wn * WN + ni * 16 + rsub) * BK + ksub];
#pragma unroll
    for (int mi = 0; mi < WIN_M; ++mi)
#pragma unroll
      for (int ni = 0; ni < WIN_N; ++ni)
        acc[mi][ni] = __builtin_amdgcn_mfma_f32_16x16x32_bf16(af[mi], bfr[ni], acc[mi][ni], 0, 0, 0);
    __syncthreads();
  }
#pragma unroll
  for (int mi = 0; mi < WIN_M; ++mi)
#pragma unroll
    for (int ni = 0; ni < WIN_N; ++ni) {
      const int col = n0 + wn * WN + ni * 16 + (lane & 15);
      const int row0 = m0 + wm * WM + mi * 16 + (lane >> 4) * 4;
      const float bv = bias ? bias[col] : 0.f;
#pragma unroll
      for (int r = 0; r < 4; ++r) {
        float v = acc[mi][ni][r] + bv;
        v = gelu_f(v);
        if (epi == 2 && (col >> 9) == 1) v *= kSCALE;
        if (epi == 3) v += res[(size_t)(row0 + r) * N + col];
        out[(size_t)(row0 + r) * N + col] = v;
      }
    }
}

// ---------------- theta-shift + head repack: qkvg -> qr,kr bf16 (B,H,T,64) ----------------
__global__ __launch_bounds__(256) void theta_k(const float* __restrict__ qkvg, const float* __restrict__ tc,
                                               const float* __restrict__ ts, bf16_t* __restrict__ qr,
                                               bf16_t* __restrict__ kr) {
  typedef __bf16 bf16x2 __attribute__((ext_vector_type(2)));
  const int tid = blockIdx.x * 256 + threadIdx.x;  // 2^20
  const int i = tid & 31, h = (tid >> 5) & 7, t = (tid >> 8) & 2047, b = tid >> 19;
  const size_t srow = ((size_t)(b * Tc + t)) * 2048 + h * 64 + 2 * i;
  const float2 q = *(const float2*)&qkvg[srow];
  const float2 k = *(const float2*)&qkvg[srow + 512];
  const float c = tc[t * 32 + i], s = ts[t * 32 + i];
  const size_t drow = (((size_t)(b * Hc + h)) * Tc + t) * 64 + 2 * i;
  bf16x2 o;
  o[0] = (bf16_t)(q.x * c - q.y * s); o[1] = (bf16_t)(q.y * c + q.x * s);
  *(bf16x2*)&qr[drow] = o;
  o[0] = (bf16_t)(k.x * c - k.y * s); o[1] = (bf16_t)(k.y * c + k.x * s);
  *(bf16x2*)&kr[drow] = o;
}

// ---------------- V transpose: qkvg v-slice (f32) -> VT[bh][d][t] (bf16) ----------------
__global__ __launch_bounds__(256) void vtrans_k(const float* __restrict__ qkvg, bf16_t* __restrict__ vt) {
  const int bh = blockIdx.y, t0 = blockIdx.x * 64;
  const int b = bh >> 3, h = bh & 7;
#pragma unroll
  for (int it = 0; it < 2; ++it) {
    const int idx = it * 256 + threadIdx.x;
    const int d = idx >> 3, tc8 = (idx & 7) * 8;
    const float* src = qkvg + (size_t)(b * Tc + t0 + tc8) * 2048 + 1024 + h * 64 + d;
    bf16x8 o;
#pragma unroll
    for (int k = 0; k < 8; ++k) o[k] = (bf16_t)src[(size_t)k * 2048];
    *(bf16x8*)&vt[(size_t)(bh * 64 + d) * Tc + t0 + tc8] = o;
  }
}

// ---------------- retention: paired q-tiles, s-parity wave split, no atomics ----------------
// grid (16 qpair, 16 bh), 512 threads = 8 waves: wave = half*4 + sub.
// Block does q = qp then q = 31-qp (33 tiles total, uniform across blocks).
// NOTE: LOADK/LOADV/TILE all take the TILE INDEX; TILE derives s0g = tile*64
// internally (R3 bug: tile index was used directly as the global s offset).
#define LOADK(st_, kf_)                                                              \
  {                                                                                  \
    const bf16_t* kb_ = kr + base + (size_t)(st_)*64 * 64;                           \
    _Pragma("unroll") for (int sc = 0; sc < 4; ++sc) {                               \
      const bf16_t* kp_ = kb_ + (size_t)(sc * 16 + li) * 64 + gi * 8;                \
      kf_[sc][0] = *(const bf16x8*)kp_;                                              \
      kf_[sc][1] = *(const bf16x8*)(kp_ + 32);                                       \
    }                                                                                \
  }
#define LOADV(st_, vf_)                                                              \
  {                                                                                  \
    _Pragma("unroll") for (int dd = 0; dd < 4; ++dd) {                               \
      const bf16_t* vp_ = vt + (size_t)(bh * 64 + dd * 16 + li) * Tc + (st_)*64 + gi * 8; \
      vf_[dd][0] = *(const bf16x8*)vp_;                                              \
      vf_[dd][1] = *(const bf16x8*)(vp_ + 32);                                       \
    }                                                                                \
  }
#define TILE(kf_, vf_, t_)                                                           \
  {                                                                                  \
    const int s0g_ = (t_)*64;                                                        \
    float aT_[4];                                                                    \
    _Pragma("unroll") for (int r = 0; r < 4; ++r)                                    \
        aT_[r] = exp2f(d2 * (float)(tw + gi * 4 + r - s0g_));                        \
    _Pragma("unroll") for (int sc = 0; sc < 4; ++sc) {                               \
      f32x4 Sv_ = {};                                                                \
      Sv_ = __builtin_amdgcn_mfma_f32_16x16x32_bf16(qf0, kf_[sc][0], Sv_, 0, 0, 0);  \
      Sv_ = __builtin_amdgcn_mfma_f32_16x16x32_bf16(qf1, kf_[sc][1], Sv_, 0, 0, 0);  \
      const int s_l_ = sc * 16 + li;                                                 \
      _Pragma("unroll") for (int r = 0; r < 4; ++r) {                                \
        const float w_ = (s0g_ + s_l_ <= tw + gi * 4 + r) ? aT_[r] * bS[sc] : 0.f;   \
        const float val_ = Sv_[r] * w_;                                              \
        rs[r] += val_;                                                               \
        sS[wave][gi * 4 + r][s_l_] = (bf16_t)val_;                                   \
      }                                                                              \
    }                                                                                \
    const bf16x8 pa0_ = *(const bf16x8*)&sS[wave][li][gi * 8];                       \
    const bf16x8 pa1_ = *(const bf16x8*)&sS[wave][li][32 + gi * 8];                  \
    _Pragma("unroll") for (int dd = 0; dd < 4; ++dd) {                               \
      accv[dd] = __builtin_amdgcn_mfma_f32_16x16x32_bf16(pa0_, vf_[dd][0], accv[dd], 0, 0, 0); \
      accv[dd] = __builtin_amdgcn_mfma_f32_16x16x32_bf16(pa1_, vf_[dd][1], accv[dd], 0, 0, 0); \
    }                                                                                \
  }

__global__ __launch_bounds__(512) void retention_k(const bf16_t* __restrict__ qr, const bf16_t* __restrict__ kr,
                                                   const bf16_t* __restrict__ vt, float* __restrict__ ao) {
  const int qp = blockIdx.x, bh = blockIdx.y;
  const int h = bh & 7, b = bh >> 3;
  const int wave = threadIdx.x >> 6, lane = threadIdx.x & 63;
  const int sub = wave & 3, half = wave >> 2;
  const int gi = lane >> 4, li = lane & 15;
  const float dec = log1pf(-exp2f(-5.f - (float)h));
  const float d2 = dec * 1.44269504088896340736f;
  const float inv1md = exp2f(5.f + (float)h);  // 1/(1-e^dec)
  __shared__ bf16_t sS[8][16][76];    // per-wave P tile (write: 4 disjoint 8-bank groups; read b128 <=2-way)
  __shared__ float red[4][64][21];    // cross-half reduction, stride 21 (gcd(21,32)=1)
  const size_t base = (size_t)bh * (size_t)Tc * 64;
  float bS[4];
#pragma unroll
  for (int sc = 0; sc < 4; ++sc) bS[sc] = exp2f(-d2 * (float)(sc * 16 + li));

  for (int part = 0; part < 2; ++part) {
    const int q = part ? (31 - qp) : qp;
    const int tw = q * 64 + sub * 16;
    bf16x8 qf0, qf1;
    {
      const bf16_t* qptr = qr + base + (size_t)(tw + li) * 64 + gi * 8;
      qf0 = *(const bf16x8*)qptr;
      qf1 = *(const bf16x8*)(qptr + 32);
    }
    f32x4 accv[4] = {};
    float rs[4] = {0.f, 0.f, 0.f, 0.f};

    // 2-deep register ping-pong over this wave's s-tiles (st = half, half+2, ...)
    bf16x8 kfA[4][2], vfA[4][2], kfB[4][2], vfB[4][2];
    int st = half;
    if (st <= q) { LOADK(st, kfA); LOADV(st, vfA); }
    while (st <= q) {
      const int n1 = st + 2;
      if (n1 <= q) { LOADK(n1, kfB); LOADV(n1, vfB); }
      TILE(kfA, vfA, st);
      st = n1;
      if (st > q) break;
      const int n2 = st + 2;
      if (n2 <= q) { LOADK(n2, kfA); LOADV(n2, vfA); }
      TILE(kfB, vfB, st);
      st = n2;
    }

    // reduce row-sums within the 16-lane group
#pragma unroll
    for (int r = 0; r < 4; ++r) {
      float v = rs[r];
      v += __shfl_xor(v, 1); v += __shfl_xor(v, 2); v += __shfl_xor(v, 4); v += __shfl_xor(v, 8);
      rs[r] = v;
    }
    // cross-half combine via LDS, then half=0 normalizes + stores
    if (half == 1) {
      float* rp = red[sub][lane];
#pragma unroll
      for (int dd = 0; dd < 4; ++dd)
#pragma unroll
        for (int r = 0; r < 4; ++r) rp[dd * 4 + r] = accv[dd][r];
#pragma unroll
      for (int r = 0; r < 4; ++r) rp[16 + r] = rs[r];
    }
    __syncthreads();
    if (half == 0) {
      const float* rp = red[sub][lane];
#pragma unroll
      for (int r = 0; r < 4; ++r) {
        const int t = tw + gi * 4 + r;
        const float Ssum = -expm1f(dec * (float)(t + 1)) * inv1md;
        const float rt = rsqrtf(Ssum);
        const float rsv = rs[r] + rp[16 + r];
        const float den = fmaxf(fabsf(rsv * rt), 1.0f) + kEPS;
        const float scl = rt / den;
        float* op = ao + ((size_t)(b * Tc + t)) * Cc + h * 64 + li;
#pragma unroll
        for (int dd = 0; dd < 4; ++dd) op[dd * 16] = (accv[dd][r] + rp[dd * 4 + r]) * scl;
      }
    }
    __syncthreads();
  }
}

// ---------------- post-retention: LN(ao) * silu(g) -> bf16 ----------------
__global__ __launch_bounds__(256) void postret_k(const float* __restrict__ ao, const float* __restrict__ qkvg,
                                                 bf16_t* __restrict__ gated) {
  const int row = blockIdx.x;
  const float* rp = ao + (size_t)row * 512;
  float v0 = rp[threadIdx.x], v1 = rp[threadIdx.x + 256];
  float s = v0 + v1, sq = v0 * v0 + v1 * v1;
#pragma unroll
  for (int m = 1; m < 64; m <<= 1) { s += __shfl_xor(s, m); sq += __shfl_xor(sq, m); }
  __shared__ float red[8];
  const int wave = threadIdx.x >> 6, lane = threadIdx.x & 63;
  if (lane == 0) { red[wave] = s; red[4 + wave] = sq; }
  __syncthreads();
  s = red[0] + red[1] + red[2] + red[3];
  sq = red[4] + red[5] + red[6] + red[7];
  const float mean = s * (1.f / 512.f);
  const float inv = rsqrtf(sq * (1.f / 512.f) - mean * mean + kEPS);
  const float* gp = qkvg + (size_t)row * 2048 + 1536;
  const float g0 = gp[threadIdx.x], g1 = gp[threadIdx.x + 256];
  bf16_t* op = gated + (size_t)row * 512;
  op[threadIdx.x] = (bf16_t)(g0 / (1.f + expf(-g0)) * (v0 - mean) * inv);
  op[threadIdx.x + 256] = (bf16_t)(g1 / (1.f + expf(-g1)) * (v1 - mean) * inv);
}

extern "C" void kernel_launch(void* const* d_in, const int* in_sizes, int n_in,
                              void* d_out, int out_size, void* d_ws, size_t ws_size,
                              hipStream_t stream) {
  const float* x_in = (const float*)d_in[0];
  const float* Wq = (const float*)d_in[1];
  const float* bq = (const float*)d_in[2];
  const float* Wk = (const float*)d_in[3];
  const float* bk = (const float*)d_in[4];
  const float* Wv = (const float*)d_in[5];
  const float* bv = (const float*)d_in[6];
  const float* Wg = (const float*)d_in[7];
  const float* bg = (const float*)d_in[8];
  const float* Wo = (const float*)d_in[9];
  const float* bo = (const float*)d_in[10];
  const float* W1 = (const float*)d_in[11];
  const float* b1 = (const float*)d_in[12];
  const float* W2 = (const float*)d_in[13];
  const float* b2 = (const float*)d_in[14];

  char* ws = (char*)d_ws;
  bf16_t* WQKVG = (bf16_t*)(ws + OFF_WQKVG);
  bf16_t* WOt   = (bf16_t*)(ws + OFF_WO);
  bf16_t* W1t   = (bf16_t*)(ws + OFF_W1);
  bf16_t* W2t   = (bf16_t*)(ws + OFF_W2);
  float*  BQKVG = (float*)(ws + OFF_BQKVG);
  float*  TABC  = (float*)(ws + OFF_TABC);
  float*  TABS  = (float*)(ws + OFF_TABS);
  bf16_t* HLN   = (bf16_t*)(ws + OFF_HLN);
  float*  QKVG  = (float*)(ws + OFF_QKVG);
  bf16_t* QR    = (bf16_t*)(ws + OFF_QR);
  bf16_t* KR    = (bf16_t*)(ws + OFF_KR);
  bf16_t* VT    = (bf16_t*)(ws + OFF_VT);
  float*  AO    = (float*)(ws + OFF_AO);
  bf16_t* GATED = (bf16_t*)(ws + OFF_GATED);
  float*  xbuf  = (float*)d_out;

  hipMemcpyAsync(xbuf, x_in, (size_t)Mc * Cc * 4, hipMemcpyDeviceToDevice, stream);

  // ---- prep ----
  const dim3 tb(32, 8);
  const float* wsrc[4] = {Wq, Wk, Wv, Wg};
  for (int c = 0; c < 4; ++c)
    transpose_pack_k<<<dim3(Cc / 32, Cc / 32, Lc), tb, 0, stream>>>(
        wsrc[c], WQKVG + (size_t)c * Cc * Cc, Cc, Cc, (size_t)Cc * Cc, (size_t)2048 * Cc);
  transpose_pack_k<<<dim3(Cc / 32, Cc / 32, Lc), tb, 0, stream>>>(
      Wo, WOt, Cc, Cc, (size_t)Cc * Cc, (size_t)Cc * Cc);
  transpose_pack_k<<<dim3(FFNc / 32, Cc / 32, Lc), tb, 0, stream>>>(
      W1, W1t, Cc, FFNc, (size_t)Cc * FFNc, (size_t)FFNc * Cc);
  transpose_pack_k<<<dim3(Cc / 32, FFNc / 32, Lc), tb, 0, stream>>>(
      W2, W2t, FFNc, Cc, (size_t)FFNc * Cc, (size_t)Cc * FFNc);
  biaspack_k<<<32, 256, 0, stream>>>(bq, bk, bv, bg, BQKVG);
  trig_k<<<256, 256, 0, stream>>>(TABC, TABS);

  for (int l = 0; l < Lc; ++l) {
    // retention block
    ln_k<512><<<Mc, 256, 0, stream>>>(xbuf, HLN);
    gemm_k<128, 128, 64, 64><<<dim3(2048 / 128, Mc / 128), 256, 0, stream>>>(
        HLN, WQKVG + (size_t)l * 2048 * 512, BQKVG + l * 2048, nullptr, QKVG, Mc, 2048, 512, 2);
    theta_k<<<(1 << 20) / 256, 256, 0, stream>>>(QKVG, TABC, TABS, QR, KR);
    vtrans_k<<<dim3(Tc / 64, Bc * Hc), 256, 0, stream>>>(QKVG, VT);
    retention_k<<<dim3(16, Bc * Hc), 512, 0, stream>>>(QR, KR, VT, AO);
    postret_k<<<Mc, 256, 0, stream>>>(AO, QKVG, GATED);
    gemm_k<128, 64, 64, 32><<<dim3(512 / 64, Mc / 128), 256, 0, stream>>>(
        GATED, WOt + (size_t)l * 512 * 512, bo + l * 512, xbuf, xbuf, Mc, 512, 512, 3);
    // FFN block
    ln_k<512><<<Mc, 256, 0, stream>>>(xbuf, HLN);
    gemm_k<128, 128, 64, 64><<<dim3(2048 / 128, Mc / 128), 256, 0, stream>>>(
        HLN, W1t + (size_t)l * 2048 * 512, b1 + l * 2048, nullptr, QKVG, Mc, 2048, 512, 1);
    ln_k<2048><<<Mc, 256, 0, stream>>>(QKVG, HLN);
    gemm_k<128, 64, 64, 32><<<dim3(512 / 64, Mc / 128), 256, 0, stream>>>(
        HLN, W2t + (size_t)l * 512 * 2048, b2 + l * 512, xbuf, xbuf, Mc, 512, 2048, 3);
  }
}

// Round 5
// 1033.021 us; speedup vs baseline: 1.5434x; 1.0324x over previous
//
#include <hip/hip_runtime.h>
#include <math.h>

typedef __bf16 bf16_t;
typedef __bf16 bf16x4 __attribute__((ext_vector_type(4)));
typedef __bf16 bf16x8 __attribute__((ext_vector_type(8)));
typedef float f32x4 __attribute__((ext_vector_type(4)));

#define DEV __device__ __forceinline__

constexpr int Bc = 2, Tc = 2048, Cc = 512, Hc = 8, FFNc = 2048, Lc = 4;
constexpr int Mc = Bc * Tc;           // 4096 rows
constexpr float kSCALE = 0.125f;      // KD^-0.5, KD=64
constexpr float kEPS = 1e-6f;

// ---------------- workspace layout (bytes) ----------------
constexpr size_t OFF_WQKVG = 0;                                    // L*2048*512 bf16
constexpr size_t OFF_WO    = OFF_WQKVG + (size_t)Lc*2048*512*2;    // L*512*512 bf16
constexpr size_t OFF_W1    = OFF_WO    + (size_t)Lc*512*512*2;     // L*2048*512 bf16
constexpr size_t OFF_W2    = OFF_W1    + (size_t)Lc*2048*512*2;    // L*512*2048 bf16
constexpr size_t OFF_BQKVG = OFF_W2    + (size_t)Lc*512*2048*2;    // L*2048 f32
constexpr size_t OFF_TABC  = OFF_BQKVG + (size_t)Lc*2048*4;        // 2048*32 f32
constexpr size_t OFF_TABS  = OFF_TABC  + (size_t)Tc*32*4;
constexpr size_t OFF_HLN   = OFF_TABS  + (size_t)Tc*32*4;          // 4096*2048 bf16
constexpr size_t OFF_QKVG  = OFF_HLN   + (size_t)Mc*2048*2;        // 4096*2048 f32 (g slice + FFN h1)
constexpr size_t OFF_QR    = OFF_QKVG  + (size_t)Mc*2048*4;        // (B,H,T,64) bf16
constexpr size_t OFF_KR    = OFF_QR    + (size_t)Bc*Hc*Tc*64*2;
constexpr size_t OFF_VT    = OFF_KR    + (size_t)Bc*Hc*Tc*64*2;    // (B,H,64,T) bf16 transposed V
constexpr size_t OFF_AO    = OFF_VT    + (size_t)Bc*Hc*64*Tc*2;    // 4096*512 f32 normalized retention out
constexpr size_t OFF_GATED = OFF_AO    + (size_t)Mc*512*4;         // 4096*512 bf16

DEV float gelu_f(float x) { return 0.5f * x * (1.0f + erff(x * 0.70710678118654752f)); }

DEV void async_load16(const void* g, void* l) {
  __builtin_amdgcn_global_load_lds((const __attribute__((address_space(1))) unsigned int*)g,
                                   (__attribute__((address_space(3))) unsigned int*)l, 16, 0, 0);
}

// ---------------- weight transpose+pack: dst[n*K+k] = bf16(src[k*N+n]) ----------------
__global__ __launch_bounds__(256) void transpose_pack_k(const float* __restrict__ src, bf16_t* __restrict__ dst,
                                                        int K, int N, size_t src_lstride, size_t dst_lstride) {
  __shared__ float tile[32][33];
  src += blockIdx.z * src_lstride;
  dst += blockIdx.z * dst_lstride;
  const int n0 = blockIdx.x * 32, k0 = blockIdx.y * 32;
  const int tx = threadIdx.x, ty = threadIdx.y;  // (32,8)
#pragma unroll
  for (int j = 0; j < 32; j += 8) tile[ty + j][tx] = src[(size_t)(k0 + ty + j) * N + n0 + tx];
  __syncthreads();
#pragma unroll
  for (int j = 0; j < 32; j += 8) dst[(size_t)(n0 + ty + j) * K + k0 + tx] = (bf16_t)tile[tx][ty + j];
}

__global__ __launch_bounds__(256) void biaspack_k(const float* __restrict__ bq, const float* __restrict__ bk,
                                                  const float* __restrict__ bv, const float* __restrict__ bg,
                                                  float* __restrict__ outp) {
  const int tid = blockIdx.x * 256 + threadIdx.x;  // L*2048
  const int l = tid >> 11, n = tid & 2047;
  const float* srcs[4] = {bq, bk, bv, bg};
  outp[tid] = srcs[n >> 9][l * 512 + (n & 511)];
}

__global__ __launch_bounds__(256) void trig_k(float* __restrict__ tc, float* __restrict__ ts) {
  const int tid = blockIdx.x * 256 + threadIdx.x;  // 65536
  const int t = tid >> 5, i = tid & 31;
  const float angle = powf(10000.f, -(float)i / 31.f);
  const float a = (float)t * angle;
  tc[tid] = cosf(a);
  ts[tid] = sinf(a);
}

// ---------------- LayerNorm (no affine) fp32 in -> bf16 out ----------------
template <int NC>
__global__ __launch_bounds__(256) void ln_k(const float* __restrict__ in, bf16_t* __restrict__ out) {
  constexpr int PT = NC / 256;
  const int row = blockIdx.x;
  const float* rp = in + (size_t)row * NC;
  float v[PT], s = 0.f, sq = 0.f;
#pragma unroll
  for (int i = 0; i < PT; ++i) { v[i] = rp[threadIdx.x + i * 256]; s += v[i]; sq += v[i] * v[i]; }
#pragma unroll
  for (int m = 1; m < 64; m <<= 1) { s += __shfl_xor(s, m); sq += __shfl_xor(sq, m); }
  __shared__ float red[8];
  const int wave = threadIdx.x >> 6, lane = threadIdx.x & 63;
  if (lane == 0) { red[wave] = s; red[4 + wave] = sq; }
  __syncthreads();
  s = red[0] + red[1] + red[2] + red[3];
  sq = red[4] + red[5] + red[6] + red[7];
  const float mean = s * (1.f / NC);
  const float inv = rsqrtf(sq * (1.f / NC) - mean * mean + kEPS);
  bf16_t* op = out + (size_t)row * NC;
#pragma unroll
  for (int i = 0; i < PT; ++i) op[threadIdx.x + i * 256] = (bf16_t)((v[i] - mean) * inv);
}

// ---------------- GEMM: out(f32) = epi(A(bf16, MxK) @ Bt(bf16, NxK)^T + bias) ----------------
// EPI 1: gelu -> out.  EPI 3: gelu + residual -> out.
// EPI 2 (fused qkvg): gelu; region by col>>9: 0=q -> theta -> QR; 1=k -> *SCALE, theta -> KR;
//                     2=v -> VT (transposed); 3=g -> out (QKVG f32, g slice only).
template <int BM, int BN, int WM, int WN, int EPI>
__global__ __launch_bounds__(256) void gemm_k(const bf16_t* __restrict__ A, const bf16_t* __restrict__ Bt,
                                              const float* __restrict__ bias, const float* __restrict__ res,
                                              float* __restrict__ out, int M, int N, int K,
                                              const float* __restrict__ tabc, const float* __restrict__ tabs,
                                              bf16_t* __restrict__ qrp, bf16_t* __restrict__ krp,
                                              bf16_t* __restrict__ vtp) {
  constexpr int BK = 32;
  constexpr int WIN_M = WM / 16, WIN_N = WN / 16;
  __shared__ bf16_t lA[BM * BK];
  __shared__ bf16_t lB[BN * BK];
  const int wave = threadIdx.x >> 6, lane = threadIdx.x & 63;
  // bijective XCD swizzle (nwg % 8 == 0 for all our grids): per-XCD contiguous row-strips
  const int nwg = gridDim.x * gridDim.y;
  const int orig = blockIdx.y * gridDim.x + blockIdx.x;
  const int wg = (orig & 7) * (nwg >> 3) + (orig >> 3);
  const int bx = wg % gridDim.x, by = wg / gridDim.x;
  const int m0 = by * BM, n0 = bx * BN;
  const int wm = wave >> 1, wn = wave & 1;
  f32x4 acc[WIN_M][WIN_N] = {};
  const int lrow = lane >> 2, lcb = (lane & 3) * 8;
  const int ksub = (lane >> 4) * 8, rsub = lane & 15;
  for (int kt = 0; kt < K; kt += BK) {
    for (int i = wave; i < BM / 16; i += 4)
      async_load16(A + (size_t)(m0 + i * 16 + lrow) * K + kt + lcb, &lA[i * 16 * BK]);
    for (int i = wave; i < BN / 16; i += 4)
      async_load16(Bt + (size_t)(n0 + i * 16 + lrow) * K + kt + lcb, &lB[i * 16 * BK]);
    __syncthreads();
    bf16x8 af[WIN_M], bfr[WIN_N];
#pragma unroll
    for (int mi = 0; mi < WIN_M; ++mi) af[mi] = *(const bf16x8*)&lA[(wm * WM + mi * 16 + rsub) * BK + ksub];
#pragma unroll
    for (int ni = 0; ni < WIN_N; ++ni) bfr[ni] = *(const bf16x8*)&lB[(wn * WN + ni * 16 + rsub) * BK + ksub];
#pragma unroll
    for (int mi = 0; mi < WIN_M; ++mi)
#pragma unroll
      for (int ni = 0; ni < WIN_N; ++ni)
        acc[mi][ni] = __builtin_amdgcn_mfma_f32_16x16x32_bf16(af[mi], bfr[ni], acc[mi][ni], 0, 0, 0);
    __syncthreads();
  }
#pragma unroll
  for (int mi = 0; mi < WIN_M; ++mi)
#pragma unroll
    for (int ni = 0; ni < WIN_N; ++ni) {
      const int col = n0 + wn * WN + ni * 16 + (lane & 15);
      const int row0 = m0 + wm * WM + mi * 16 + (lane >> 4) * 4;
      const float bv = bias ? bias[col] : 0.f;
      if constexpr (EPI == 2) {
        const int region = col >> 9;  // wave-uniform (block's 128 cols sit in one 512-region)
        if (region <= 1) {
          const int hh = (col >> 6) & 7, d = col & 63, ti = d >> 1;
          bf16_t* dst = region ? krp : qrp;
#pragma unroll
          for (int r = 0; r < 4; ++r) {
            float v = gelu_f(acc[mi][ni][r] + bv);
            if (region == 1) v *= kSCALE;
            const float p = __shfl_xor(v, 1);  // partner col c^1 (lane bit0 == col bit0)
            const int m = row0 + r, t = m & 2047, bb = m >> 11;
            const float cv = tabc[t * 32 + ti], sv = tabs[t * 32 + ti];
            const float rot = (d & 1) ? p : -p;  // rotate_every_two
            dst[((size_t)((bb * 8 + hh) * 2048 + t)) * 64 + d] = (bf16_t)(v * cv + rot * sv);
          }
        } else if (region == 2) {
          const int hh = (col >> 6) & 7, d = col & 63;
          const int m = row0, t0 = m & 2047, bb = m >> 11;
          bf16x4 pk;
#pragma unroll
          for (int r = 0; r < 4; ++r) pk[r] = (bf16_t)gelu_f(acc[mi][ni][r] + bv);
          *(bf16x4*)&vtp[((size_t)((bb * 8 + hh) * 64 + d)) * 2048 + t0] = pk;
        } else {
#pragma unroll
          for (int r = 0; r < 4; ++r)
            out[(size_t)(row0 + r) * N + col] = gelu_f(acc[mi][ni][r] + bv);
        }
      } else {
#pragma unroll
        for (int r = 0; r < 4; ++r) {
          float v = gelu_f(acc[mi][ni][r] + bv);
          if constexpr (EPI == 3) v += res[(size_t)(row0 + r) * N + col];
          out[(size_t)(row0 + r) * N + col] = v;
        }
      }
    }
}

// ---------------- retention: paired q-tiles, s-parity wave split, XCD-local bh ----------------
// 1D grid 256: xcd=bid&7 owns bh {2*xcd, 2*xcd+1} (per-XCD working set ~1.5MB << 4MB L2).
// 512 threads = 8 waves: wave = half*4 + sub. Block does q=qp then q=31-qp (33 tiles, uniform).
#define LOADK(st_, kf_)                                                              \
  {                                                                                  \
    const bf16_t* kb_ = kr + base + (size_t)(st_)*64 * 64;                           \
    _Pragma("unroll") for (int sc = 0; sc < 4; ++sc) {                               \
      const bf16_t* kp_ = kb_ + (size_t)(sc * 16 + li) * 64 + gi * 8;                \
      kf_[sc][0] = *(const bf16x8*)kp_;                                              \
      kf_[sc][1] = *(const bf16x8*)(kp_ + 32);                                       \
    }                                                                                \
  }
#define LOADV(st_, vf_)                                                              \
  {                                                                                  \
    _Pragma("unroll") for (int dd = 0; dd < 4; ++dd) {                               \
      const bf16_t* vp_ = vt + (size_t)(bh * 64 + dd * 16 + li) * Tc + (st_)*64 + gi * 8; \
      vf_[dd][0] = *(const bf16x8*)vp_;                                              \
      vf_[dd][1] = *(const bf16x8*)(vp_ + 32);                                       \
    }                                                                                \
  }
#define TILE(kf_, vf_, t_)                                                           \
  {                                                                                  \
    const int s0g_ = (t_)*64;                                                        \
    float aT_[4];                                                                    \
    _Pragma("unroll") for (int r = 0; r < 4; ++r)                                    \
        aT_[r] = exp2f(d2 * (float)(tw + gi * 4 + r - s0g_));                        \
    _Pragma("unroll") for (int sc = 0; sc < 4; ++sc) {                               \
      f32x4 Sv_ = {};                                                                \
      Sv_ = __builtin_amdgcn_mfma_f32_16x16x32_bf16(qf0, kf_[sc][0], Sv_, 0, 0, 0);  \
      Sv_ = __builtin_amdgcn_mfma_f32_16x16x32_bf16(qf1, kf_[sc][1], Sv_, 0, 0, 0);  \
      const int s_l_ = sc * 16 + li;                                                 \
      _Pragma("unroll") for (int r = 0; r < 4; ++r) {                                \
        const float w_ = (s0g_ + s_l_ <= tw + gi * 4 + r) ? aT_[r] * bS[sc] : 0.f;   \
        const float val_ = Sv_[r] * w_;                                              \
        rs[r] += val_;                                                               \
        sS[wave][gi * 4 + r][s_l_] = (bf16_t)val_;                                   \
      }                                                                              \
    }                                                                                \
    const bf16x8 pa0_ = *(const bf16x8*)&sS[wave][li][gi * 8];                       \
    const bf16x8 pa1_ = *(const bf16x8*)&sS[wave][li][32 + gi * 8];                  \
    _Pragma("unroll") for (int dd = 0; dd < 4; ++dd) {                               \
      accv[dd] = __builtin_amdgcn_mfma_f32_16x16x32_bf16(pa0_, vf_[dd][0], accv[dd], 0, 0, 0); \
      accv[dd] = __builtin_amdgcn_mfma_f32_16x16x32_bf16(pa1_, vf_[dd][1], accv[dd], 0, 0, 0); \
    }                                                                                \
  }

__global__ __launch_bounds__(512) void retention_k(const bf16_t* __restrict__ qr, const bf16_t* __restrict__ kr,
                                                   const bf16_t* __restrict__ vt, float* __restrict__ ao) {
  const int bid = blockIdx.x;          // 0..255
  const int j = bid >> 3;              // 0..31
  const int bh = (bid & 7) * 2 + (j & 1);
  const int qp = j >> 1;               // 0..15
  const int h = bh & 7, b = bh >> 3;
  const int wave = threadIdx.x >> 6, lane = threadIdx.x & 63;
  const int sub = wave & 3, half = wave >> 2;
  const int gi = lane >> 4, li = lane & 15;
  const float dec = log1pf(-exp2f(-5.f - (float)h));
  const float d2 = dec * 1.44269504088896340736f;
  const float inv1md = exp2f(5.f + (float)h);  // 1/(1-e^dec)
  __shared__ bf16_t sS[8][16][76];    // per-wave P tile
  __shared__ float red[4][64][21];    // cross-half reduction, stride 21
  const size_t base = (size_t)bh * (size_t)Tc * 64;
  float bS[4];
#pragma unroll
  for (int sc = 0; sc < 4; ++sc) bS[sc] = exp2f(-d2 * (float)(sc * 16 + li));

  for (int part = 0; part < 2; ++part) {
    const int q = part ? (31 - qp) : qp;
    const int tw = q * 64 + sub * 16;
    bf16x8 qf0, qf1;
    {
      const bf16_t* qptr = qr + base + (size_t)(tw + li) * 64 + gi * 8;
      qf0 = *(const bf16x8*)qptr;
      qf1 = *(const bf16x8*)(qptr + 32);
    }
    f32x4 accv[4] = {};
    float rs[4] = {0.f, 0.f, 0.f, 0.f};

    // 2-deep register ping-pong over this wave's s-tiles (st = half, half+2, ...)
    bf16x8 kfA[4][2], vfA[4][2], kfB[4][2], vfB[4][2];
    int st = half;
    if (st <= q) { LOADK(st, kfA); LOADV(st, vfA); }
    while (st <= q) {
      const int n1 = st + 2;
      if (n1 <= q) { LOADK(n1, kfB); LOADV(n1, vfB); }
      TILE(kfA, vfA, st);
      st = n1;
      if (st > q) break;
      const int n2 = st + 2;
      if (n2 <= q) { LOADK(n2, kfA); LOADV(n2, vfA); }
      TILE(kfB, vfB, st);
      st = n2;
    }

    // reduce row-sums within the 16-lane group
#pragma unroll
    for (int r = 0; r < 4; ++r) {
      float v = rs[r];
      v += __shfl_xor(v, 1); v += __shfl_xor(v, 2); v += __shfl_xor(v, 4); v += __shfl_xor(v, 8);
      rs[r] = v;
    }
    // cross-half combine via LDS, then half=0 normalizes + stores
    if (half == 1) {
      float* rp = red[sub][lane];
#pragma unroll
      for (int dd = 0; dd < 4; ++dd)
#pragma unroll
        for (int r = 0; r < 4; ++r) rp[dd * 4 + r] = accv[dd][r];
#pragma unroll
      for (int r = 0; r < 4; ++r) rp[16 + r] = rs[r];
    }
    __syncthreads();
    if (half == 0) {
      const float* rp = red[sub][lane];
#pragma unroll
      for (int r = 0; r < 4; ++r) {
        const int t = tw + gi * 4 + r;
        const float Ssum = -expm1f(dec * (float)(t + 1)) * inv1md;
        const float rt = rsqrtf(Ssum);
        const float rsv = rs[r] + rp[16 + r];
        const float den = fmaxf(fabsf(rsv * rt), 1.0f) + kEPS;
        const float scl = rt / den;
        float* op = ao + ((size_t)(b * Tc + t)) * Cc + h * 64 + li;
#pragma unroll
        for (int dd = 0; dd < 4; ++dd) op[dd * 16] = (accv[dd][r] + rp[dd * 4 + r]) * scl;
      }
    }
    __syncthreads();
  }
}

// ---------------- post-retention: LN(ao) * silu(g) -> bf16 ----------------
__global__ __launch_bounds__(256) void postret_k(const float* __restrict__ ao, const float* __restrict__ qkvg,
                                                 bf16_t* __restrict__ gated) {
  const int row = blockIdx.x;
  const float* rp = ao + (size_t)row * 512;
  float v0 = rp[threadIdx.x], v1 = rp[threadIdx.x + 256];
  float s = v0 + v1, sq = v0 * v0 + v1 * v1;
#pragma unroll
  for (int m = 1; m < 64; m <<= 1) { s += __shfl_xor(s, m); sq += __shfl_xor(sq, m); }
  __shared__ float red[8];
  const int wave = threadIdx.x >> 6, lane = threadIdx.x & 63;
  if (lane == 0) { red[wave] = s; red[4 + wave] = sq; }
  __syncthreads();
  s = red[0] + red[1] + red[2] + red[3];
  sq = red[4] + red[5] + red[6] + red[7];
  const float mean = s * (1.f / 512.f);
  const float inv = rsqrtf(sq * (1.f / 512.f) - mean * mean + kEPS);
  const float* gp = qkvg + (size_t)row * 2048 + 1536;
  const float g0 = gp[threadIdx.x], g1 = gp[threadIdx.x + 256];
  bf16_t* op = gated + (size_t)row * 512;
  op[threadIdx.x] = (bf16_t)(g0 / (1.f + expf(-g0)) * (v0 - mean) * inv);
  op[threadIdx.x + 256] = (bf16_t)(g1 / (1.f + expf(-g1)) * (v1 - mean) * inv);
}

extern "C" void kernel_launch(void* const* d_in, const int* in_sizes, int n_in,
                              void* d_out, int out_size, void* d_ws, size_t ws_size,
                              hipStream_t stream) {
  const float* x_in = (const float*)d_in[0];
  const float* Wq = (const float*)d_in[1];
  const float* bq = (const float*)d_in[2];
  const float* Wk = (const float*)d_in[3];
  const float* bk = (const float*)d_in[4];
  const float* Wv = (const float*)d_in[5];
  const float* bv = (const float*)d_in[6];
  const float* Wg = (const float*)d_in[7];
  const float* bg = (const float*)d_in[8];
  const float* Wo = (const float*)d_in[9];
  const float* bo = (const float*)d_in[10];
  const float* W1 = (const float*)d_in[11];
  const float* b1 = (const float*)d_in[12];
  const float* W2 = (const float*)d_in[13];
  const float* b2 = (const float*)d_in[14];

  char* ws = (char*)d_ws;
  bf16_t* WQKVG = (bf16_t*)(ws + OFF_WQKVG);
  bf16_t* WOt   = (bf16_t*)(ws + OFF_WO);
  bf16_t* W1t   = (bf16_t*)(ws + OFF_W1);
  bf16_t* W2t   = (bf16_t*)(ws + OFF_W2);
  float*  BQKVG = (float*)(ws + OFF_BQKVG);
  float*  TABC  = (float*)(ws + OFF_TABC);
  float*  TABS  = (float*)(ws + OFF_TABS);
  bf16_t* HLN   = (bf16_t*)(ws + OFF_HLN);
  float*  QKVG  = (float*)(ws + OFF_QKVG);
  bf16_t* QR    = (bf16_t*)(ws + OFF_QR);
  bf16_t* KR    = (bf16_t*)(ws + OFF_KR);
  bf16_t* VT    = (bf16_t*)(ws + OFF_VT);
  float*  AO    = (float*)(ws + OFF_AO);
  bf16_t* GATED = (bf16_t*)(ws + OFF_GATED);
  float*  xbuf  = (float*)d_out;

  hipMemcpyAsync(xbuf, x_in, (size_t)Mc * Cc * 4, hipMemcpyDeviceToDevice, stream);

  // ---- prep ----
  const dim3 tb(32, 8);
  const float* wsrc[4] = {Wq, Wk, Wv, Wg};
  for (int c = 0; c < 4; ++c)
    transpose_pack_k<<<dim3(Cc / 32, Cc / 32, Lc), tb, 0, stream>>>(
        wsrc[c], WQKVG + (size_t)c * Cc * Cc, Cc, Cc, (size_t)Cc * Cc, (size_t)2048 * Cc);
  transpose_pack_k<<<dim3(Cc / 32, Cc / 32, Lc), tb, 0, stream>>>(
      Wo, WOt, Cc, Cc, (size_t)Cc * Cc, (size_t)Cc * Cc);
  transpose_pack_k<<<dim3(FFNc / 32, Cc / 32, Lc), tb, 0, stream>>>(
      W1, W1t, Cc, FFNc, (size_t)Cc * FFNc, (size_t)FFNc * Cc);
  transpose_pack_k<<<dim3(Cc / 32, FFNc / 32, Lc), tb, 0, stream>>>(
      W2, W2t, FFNc, Cc, (size_t)FFNc * Cc, (size_t)Cc * FFNc);
  biaspack_k<<<32, 256, 0, stream>>>(bq, bk, bv, bg, BQKVG);
  trig_k<<<256, 256, 0, stream>>>(TABC, TABS);

  for (int l = 0; l < Lc; ++l) {
    // retention block
    ln_k<512><<<Mc, 256, 0, stream>>>(xbuf, HLN);
    gemm_k<128, 128, 64, 64, 2><<<dim3(2048 / 128, Mc / 128), 256, 0, stream>>>(
        HLN, WQKVG + (size_t)l * 2048 * 512, BQKVG + l * 2048, nullptr, QKVG, Mc, 2048, 512,
        TABC, TABS, QR, KR, VT);
    retention_k<<<256, 512, 0, stream>>>(QR, KR, VT, AO);
    postret_k<<<Mc, 256, 0, stream>>>(AO, QKVG, GATED);
    gemm_k<128, 64, 64, 32, 3><<<dim3(512 / 64, Mc / 128), 256, 0, stream>>>(
        GATED, WOt + (size_t)l * 512 * 512, bo + l * 512, xbuf, xbuf, Mc, 512, 512,
        nullptr, nullptr, nullptr, nullptr, nullptr);
    // FFN block
    ln_k<512><<<Mc, 256, 0, stream>>>(xbuf, HLN);
    gemm_k<128, 128, 64, 64, 1><<<dim3(2048 / 128, Mc / 128), 256, 0, stream>>>(
        HLN, W1t + (size_t)l * 2048 * 512, b1 + l * 2048, nullptr, QKVG, Mc, 2048, 512,
        nullptr, nullptr, nullptr, nullptr, nullptr);
    ln_k<2048><<<Mc, 256, 0, stream>>>(QKVG, HLN);
    gemm_k<128, 64, 64, 32, 3><<<dim3(512 / 64, Mc / 128), 256, 0, stream>>>(
        HLN, W2t + (size_t)l * 512 * 2048, b2 + l * 512, xbuf, xbuf, Mc, 512, 2048,
        nullptr, nullptr, nullptr, nullptr, nullptr);
  }
}

// Round 6
// 876.105 us; speedup vs baseline: 1.8198x; 1.1791x over previous
//
#include <hip/hip_runtime.h>
#include <math.h>

typedef __bf16 bf16_t;
typedef __bf16 bf16x4 __attribute__((ext_vector_type(4)));
typedef __bf16 bf16x8 __attribute__((ext_vector_type(8)));
typedef float f32x4 __attribute__((ext_vector_type(4)));

#define DEV __device__ __forceinline__

constexpr int Bc = 2, Tc = 2048, Cc = 512, Hc = 8, FFNc = 2048, Lc = 4;
constexpr int Mc = Bc * Tc;           // 4096 rows
constexpr float kSCALE = 0.125f;      // KD^-0.5, KD=64
constexpr float kEPS = 1e-6f;

// ---------------- workspace layout (bytes) ----------------
constexpr size_t OFF_WQKVG = 0;                                    // L*2048*512 bf16
constexpr size_t OFF_WO    = OFF_WQKVG + (size_t)Lc*2048*512*2;    // L*512*512 bf16
constexpr size_t OFF_W1    = OFF_WO    + (size_t)Lc*512*512*2;     // L*2048*512 bf16
constexpr size_t OFF_W2    = OFF_W1    + (size_t)Lc*2048*512*2;    // L*512*2048 bf16
constexpr size_t OFF_BQKVG = OFF_W2    + (size_t)Lc*512*2048*2;    // L*2048 f32
constexpr size_t OFF_TABC  = OFF_BQKVG + (size_t)Lc*2048*4;        // 2048*32 f32
constexpr size_t OFF_TABS  = OFF_TABC  + (size_t)Tc*32*4;
constexpr size_t OFF_HLN   = OFF_TABS  + (size_t)Tc*32*4;          // 4096*2048 bf16
constexpr size_t OFF_QKVG  = OFF_HLN   + (size_t)Mc*2048*2;        // 4096*2048 f32 (g slice + FFN h1)
constexpr size_t OFF_QR    = OFF_QKVG  + (size_t)Mc*2048*4;        // (B,H,T,64) bf16
constexpr size_t OFF_KR    = OFF_QR    + (size_t)Bc*Hc*Tc*64*2;
constexpr size_t OFF_VT    = OFF_KR    + (size_t)Bc*Hc*Tc*64*2;    // (B,H,64,T) bf16 transposed V
constexpr size_t OFF_AO    = OFF_VT    + (size_t)Bc*Hc*64*Tc*2;    // 4096*512 f32 normalized retention out
constexpr size_t OFF_GATED = OFF_AO    + (size_t)Mc*512*4;         // 4096*512 bf16

DEV float gelu_f(float x) { return 0.5f * x * (1.0f + erff(x * 0.70710678118654752f)); }

DEV void async_load16(const void* g, void* l) {
  __builtin_amdgcn_global_load_lds((const __attribute__((address_space(1))) unsigned int*)g,
                                   (__attribute__((address_space(3))) unsigned int*)l, 16, 0, 0);
}

// ---------------- weight transpose+pack: dst[n*K+k] = bf16(src[k*N+n]) ----------------
__global__ __launch_bounds__(256) void transpose_pack_k(const float* __restrict__ src, bf16_t* __restrict__ dst,
                                                        int K, int N, size_t src_lstride, size_t dst_lstride) {
  __shared__ float tile[32][33];
  src += blockIdx.z * src_lstride;
  dst += blockIdx.z * dst_lstride;
  const int n0 = blockIdx.x * 32, k0 = blockIdx.y * 32;
  const int tx = threadIdx.x, ty = threadIdx.y;  // (32,8)
#pragma unroll
  for (int j = 0; j < 32; j += 8) tile[ty + j][tx] = src[(size_t)(k0 + ty + j) * N + n0 + tx];
  __syncthreads();
#pragma unroll
  for (int j = 0; j < 32; j += 8) dst[(size_t)(n0 + ty + j) * K + k0 + tx] = (bf16_t)tile[tx][ty + j];
}

__global__ __launch_bounds__(256) void biaspack_k(const float* __restrict__ bq, const float* __restrict__ bk,
                                                  const float* __restrict__ bv, const float* __restrict__ bg,
                                                  float* __restrict__ outp) {
  const int tid = blockIdx.x * 256 + threadIdx.x;  // L*2048
  const int l = tid >> 11, n = tid & 2047;
  const float* srcs[4] = {bq, bk, bv, bg};
  outp[tid] = srcs[n >> 9][l * 512 + (n & 511)];
}

__global__ __launch_bounds__(256) void trig_k(float* __restrict__ tc, float* __restrict__ ts) {
  const int tid = blockIdx.x * 256 + threadIdx.x;  // 65536
  const int t = tid >> 5, i = tid & 31;
  const float angle = powf(10000.f, -(float)i / 31.f);
  const float a = (float)t * angle;
  tc[tid] = cosf(a);
  ts[tid] = sinf(a);
}

// ---------------- LayerNorm (no affine) fp32 in -> bf16 out ----------------
template <int NC>
__global__ __launch_bounds__(256) void ln_k(const float* __restrict__ in, bf16_t* __restrict__ out) {
  constexpr int PT = NC / 256;
  const int row = blockIdx.x;
  const float* rp = in + (size_t)row * NC;
  float v[PT], s = 0.f, sq = 0.f;
#pragma unroll
  for (int i = 0; i < PT; ++i) { v[i] = rp[threadIdx.x + i * 256]; s += v[i]; sq += v[i] * v[i]; }
#pragma unroll
  for (int m = 1; m < 64; m <<= 1) { s += __shfl_xor(s, m); sq += __shfl_xor(sq, m); }
  __shared__ float red[8];
  const int wave = threadIdx.x >> 6, lane = threadIdx.x & 63;
  if (lane == 0) { red[wave] = s; red[4 + wave] = sq; }
  __syncthreads();
  s = red[0] + red[1] + red[2] + red[3];
  sq = red[4] + red[5] + red[6] + red[7];
  const float mean = s * (1.f / NC);
  const float inv = rsqrtf(sq * (1.f / NC) - mean * mean + kEPS);
  bf16_t* op = out + (size_t)row * NC;
#pragma unroll
  for (int i = 0; i < PT; ++i) op[threadIdx.x + i * 256] = (bf16_t)((v[i] - mean) * inv);
}

// ---------------- GEMM: out(f32) = epi(A(bf16, MxK) @ Bt(bf16, NxK)^T + bias) ----------------
// EPI 1: gelu -> out.  EPI 3: gelu + residual -> out.
// EPI 2 (fused qkvg): gelu; region by col>>9: 0=q -> theta -> QR; 1=k -> *SCALE, theta -> KR;
//                     2=v -> VT (transposed); 3=g -> out (QKVG f32, g slice only).
template <int BM, int BN, int WM, int WN, int EPI>
__global__ __launch_bounds__(256) void gemm_k(const bf16_t* __restrict__ A, const bf16_t* __restrict__ Bt,
                                              const float* __restrict__ bias, const float* __restrict__ res,
                                              float* __restrict__ out, int M, int N, int K,
                                              const float* __restrict__ tabc, const float* __restrict__ tabs,
                                              bf16_t* __restrict__ qrp, bf16_t* __restrict__ krp,
                                              bf16_t* __restrict__ vtp) {
  constexpr int BK = 32;
  constexpr int WIN_M = WM / 16, WIN_N = WN / 16;
  __shared__ bf16_t lA[BM * BK];
  __shared__ bf16_t lB[BN * BK];
  const int wave = threadIdx.x >> 6, lane = threadIdx.x & 63;
  // bijective XCD swizzle (nwg % 8 == 0 for all our grids): per-XCD contiguous row-strips
  const int nwg = gridDim.x * gridDim.y;
  const int orig = blockIdx.y * gridDim.x + blockIdx.x;
  const int wg = (orig & 7) * (nwg >> 3) + (orig >> 3);
  const int bx = wg % gridDim.x, by = wg / gridDim.x;
  const int m0 = by * BM, n0 = bx * BN;
  const int wm = wave >> 1, wn = wave & 1;
  f32x4 acc[WIN_M][WIN_N] = {};
  const int lrow = lane >> 2, lcb = (lane & 3) * 8;
  const int ksub = (lane >> 4) * 8, rsub = lane & 15;
  for (int kt = 0; kt < K; kt += BK) {
    for (int i = wave; i < BM / 16; i += 4)
      async_load16(A + (size_t)(m0 + i * 16 + lrow) * K + kt + lcb, &lA[i * 16 * BK]);
    for (int i = wave; i < BN / 16; i += 4)
      async_load16(Bt + (size_t)(n0 + i * 16 + lrow) * K + kt + lcb, &lB[i * 16 * BK]);
    __syncthreads();
    bf16x8 af[WIN_M], bfr[WIN_N];
#pragma unroll
    for (int mi = 0; mi < WIN_M; ++mi) af[mi] = *(const bf16x8*)&lA[(wm * WM + mi * 16 + rsub) * BK + ksub];
#pragma unroll
    for (int ni = 0; ni < WIN_N; ++ni) bfr[ni] = *(const bf16x8*)&lB[(wn * WN + ni * 16 + rsub) * BK + ksub];
#pragma unroll
    for (int mi = 0; mi < WIN_M; ++mi)
#pragma unroll
      for (int ni = 0; ni < WIN_N; ++ni)
        acc[mi][ni] = __builtin_amdgcn_mfma_f32_16x16x32_bf16(af[mi], bfr[ni], acc[mi][ni], 0, 0, 0);
    __syncthreads();
  }
#pragma unroll
  for (int mi = 0; mi < WIN_M; ++mi)
#pragma unroll
    for (int ni = 0; ni < WIN_N; ++ni) {
      const int col = n0 + wn * WN + ni * 16 + (lane & 15);
      const int row0 = m0 + wm * WM + mi * 16 + (lane >> 4) * 4;
      const float bv = bias ? bias[col] : 0.f;
      if constexpr (EPI == 2) {
        const int region = col >> 9;  // wave-uniform (block's 128 cols sit in one 512-region)
        if (region <= 1) {
          const int hh = (col >> 6) & 7, d = col & 63, ti = d >> 1;
          bf16_t* dst = region ? krp : qrp;
#pragma unroll
          for (int r = 0; r < 4; ++r) {
            float v = gelu_f(acc[mi][ni][r] + bv);
            if (region == 1) v *= kSCALE;
            const float p = __shfl_xor(v, 1);  // partner col c^1 (lane bit0 == col bit0)
            const int m = row0 + r, t = m & 2047, bb = m >> 11;
            const float cv = tabc[t * 32 + ti], sv = tabs[t * 32 + ti];
            const float rot = (d & 1) ? p : -p;  // rotate_every_two
            dst[((size_t)((bb * 8 + hh) * 2048 + t)) * 64 + d] = (bf16_t)(v * cv + rot * sv);
          }
        } else if (region == 2) {
          const int hh = (col >> 6) & 7, d = col & 63;
          const int m = row0, t0 = m & 2047, bb = m >> 11;
          bf16x4 pk;
#pragma unroll
          for (int r = 0; r < 4; ++r) pk[r] = (bf16_t)gelu_f(acc[mi][ni][r] + bv);
          *(bf16x4*)&vtp[((size_t)((bb * 8 + hh) * 64 + d)) * 2048 + t0] = pk;
        } else {
#pragma unroll
          for (int r = 0; r < 4; ++r)
            out[(size_t)(row0 + r) * N + col] = gelu_f(acc[mi][ni][r] + bv);
        }
      } else {
#pragma unroll
        for (int r = 0; r < 4; ++r) {
          float v = gelu_f(acc[mi][ni][r] + bv);
          if constexpr (EPI == 3) v += res[(size_t)(row0 + r) * N + col];
          out[(size_t)(row0 + r) * N + col] = v;
        }
      }
    }
}

// ---------------- retention: LDS-staged K/V, paired q-tiles, s-parity halves, XCD-local bh ----------------
// 1D grid 256: xcd=bid&7 owns bh {2*xcd, 2*xcd+1}. 512 threads = 8 waves: wave = half*4 + sub.
// Each half stages its parity tile (K+V, 16KB) into LDS via global_load_lds, double-buffered,
// one __syncthreads per step (m97 pattern). Chunk-XOR swizzle (chunk ^= row&7) applied on the
// GLOBAL SOURCE address and again on the ds_read side (rule: both-sides-or-neither).
__global__ __launch_bounds__(512) void retention_k(const bf16_t* __restrict__ qr, const bf16_t* __restrict__ kr,
                                                   const bf16_t* __restrict__ vt, float* __restrict__ ao) {
  const int bid = blockIdx.x;          // 0..255
  const int j = bid >> 3;              // 0..31
  const int bh = (bid & 7) * 2 + (j & 1);
  const int qp = j >> 1;               // 0..15
  const int h = bh & 7, b = bh >> 3;
  const int wave = threadIdx.x >> 6, lane = threadIdx.x & 63;
  const int sub = wave & 3, half = wave >> 2;
  const int gi = lane >> 4, li = lane & 15;
  const float dec = log1pf(-exp2f(-5.f - (float)h));
  const float d2 = dec * 1.44269504088896340736f;
  const float inv1md = exp2f(5.f + (float)h);  // 1/(1-e^dec)
  __shared__ bf16_t kv[2][2][2][64][64];  // [buf][half][K/V][row][col] (chunk-swizzled)
  __shared__ bf16_t sS[8][16][76];        // per-wave P tile (verified conflict-free)
  __shared__ float red[4][64][21];        // cross-half reduction, stride 21
  const size_t base = (size_t)bh * (size_t)Tc * 64;
  const bf16_t* vbh = vt + (size_t)bh * 64 * Tc;

  // staging source decomposition: lane covers (row = 8*rb + srow, chunk = schunk) of a 64x64 tile
  const int srow = lane >> 3;                 // 0..7
  const int schunk = (lane & 7) ^ srow;       // pre-swizzled source chunk (dest is linear)
  // fragment read offsets (bf16 elems within a [64][64] tile); row = (16-blk)+li, k-chunks gi / gi+4
  const int roff0 = li * 64 + (((gi) ^ (li & 7)) << 3);
  const int roff1 = li * 64 + (((gi + 4) ^ (li & 7)) << 3);

  float bS[4];
#pragma unroll
  for (int sc = 0; sc < 4; ++sc) bS[sc] = exp2f(-d2 * (float)(sc * 16 + li));

#define STAGE(bf_, st_)                                                                   \
  {                                                                                       \
    const bf16_t* kt_ = kr + base + (size_t)(st_) * 64 * 64;                              \
    const bf16_t* vt_ = vbh + (st_) * 64;                                                 \
    _Pragma("unroll") for (int jj = 0; jj < 2; ++jj) {                                    \
      const int rb_ = sub * 2 + jj;                                                       \
      async_load16(kt_ + (size_t)(rb_ * 8 + srow) * 64 + schunk * 8, &kv[bf_][half][0][rb_ * 8][0]); \
      async_load16(vt_ + (size_t)(rb_ * 8 + srow) * Tc + schunk * 8, &kv[bf_][half][1][rb_ * 8][0]); \
    }                                                                                     \
  }

  for (int part = 0; part < 2; ++part) {
    const int q = part ? (31 - qp) : qp;
    const int tw = q * 64 + sub * 16;
    bf16x8 qf0, qf1;
    {
      const bf16_t* qptr = qr + base + (size_t)(tw + li) * 64 + gi * 8;
      qf0 = *(const bf16x8*)qptr;
      qf1 = *(const bf16x8*)(qptr + 32);
    }
    f32x4 accv[4] = {};
    float rs[4] = {0.f, 0.f, 0.f, 0.f};

    const int nsteps = (q + 2) >> 1;   // ceil((q+1)/2), uniform across block
    int buf = 0;
    if (half <= q) STAGE(0, half);
    __syncthreads();
    for (int i = 0; i < nsteps; ++i) {
      const int st = 2 * i + half;
      const int stn = st + 2;
      if (stn <= q) STAGE(buf ^ 1, stn);
      if (st <= q) {
        const int s0g = st * 64;
        const bf16_t* kb = &kv[buf][half][0][0][0];
        const bf16_t* vb = &kv[buf][half][1][0][0];
        float aT[4];
#pragma unroll
        for (int r = 0; r < 4; ++r) aT[r] = exp2f(d2 * (float)(tw + gi * 4 + r - s0g));
#pragma unroll
        for (int sc = 0; sc < 4; ++sc) {
          const bf16x8 kf0 = *(const bf16x8*)(kb + sc * 16 * 64 + roff0);
          const bf16x8 kf1 = *(const bf16x8*)(kb + sc * 16 * 64 + roff1);
          f32x4 Sv = {};
          Sv = __builtin_amdgcn_mfma_f32_16x16x32_bf16(qf0, kf0, Sv, 0, 0, 0);
          Sv = __builtin_amdgcn_mfma_f32_16x16x32_bf16(qf1, kf1, Sv, 0, 0, 0);
          const int s_l = sc * 16 + li;
#pragma unroll
          for (int r = 0; r < 4; ++r) {
            const float w = (s0g + s_l <= tw + gi * 4 + r) ? aT[r] * bS[sc] : 0.f;
            const float val = Sv[r] * w;
            rs[r] += val;
            sS[wave][gi * 4 + r][s_l] = (bf16_t)val;
          }
        }
        const bf16x8 pa0 = *(const bf16x8*)&sS[wave][li][gi * 8];
        const bf16x8 pa1 = *(const bf16x8*)&sS[wave][li][32 + gi * 8];
#pragma unroll
        for (int dd = 0; dd < 4; ++dd) {
          const bf16x8 vb0 = *(const bf16x8*)(vb + dd * 16 * 64 + roff0);
          const bf16x8 vb1 = *(const bf16x8*)(vb + dd * 16 * 64 + roff1);
          accv[dd] = __builtin_amdgcn_mfma_f32_16x16x32_bf16(pa0, vb0, accv[dd], 0, 0, 0);
          accv[dd] = __builtin_amdgcn_mfma_f32_16x16x32_bf16(pa1, vb1, accv[dd], 0, 0, 0);
        }
      }
      __syncthreads();
      buf ^= 1;
    }

    // reduce row-sums within the 16-lane group
#pragma unroll
    for (int r = 0; r < 4; ++r) {
      float v = rs[r];
      v += __shfl_xor(v, 1); v += __shfl_xor(v, 2); v += __shfl_xor(v, 4); v += __shfl_xor(v, 8);
      rs[r] = v;
    }
    // cross-half combine via LDS, then half=0 normalizes + stores
    if (half == 1) {
      float* rp = red[sub][lane];
#pragma unroll
      for (int dd = 0; dd < 4; ++dd)
#pragma unroll
        for (int r = 0; r < 4; ++r) rp[dd * 4 + r] = accv[dd][r];
#pragma unroll
      for (int r = 0; r < 4; ++r) rp[16 + r] = rs[r];
    }
    __syncthreads();
    if (half == 0) {
      const float* rp = red[sub][lane];
#pragma unroll
      for (int r = 0; r < 4; ++r) {
        const int t = tw + gi * 4 + r;
        const float Ssum = -expm1f(dec * (float)(t + 1)) * inv1md;
        const float rt = rsqrtf(Ssum);
        const float rsv = rs[r] + rp[16 + r];
        const float den = fmaxf(fabsf(rsv * rt), 1.0f) + kEPS;
        const float scl = rt / den;
        float* op = ao + ((size_t)(b * Tc + t)) * Cc + h * 64 + li;
#pragma unroll
        for (int dd = 0; dd < 4; ++dd) op[dd * 16] = (accv[dd][r] + rp[dd * 4 + r]) * scl;
      }
    }
    __syncthreads();
  }
#undef STAGE
}

// ---------------- post-retention: LN(ao) * silu(g) -> bf16 ----------------
__global__ __launch_bounds__(256) void postret_k(const float* __restrict__ ao, const float* __restrict__ qkvg,
                                                 bf16_t* __restrict__ gated) {
  const int row = blockIdx.x;
  const float* rp = ao + (size_t)row * 512;
  float v0 = rp[threadIdx.x], v1 = rp[threadIdx.x + 256];
  float s = v0 + v1, sq = v0 * v0 + v1 * v1;
#pragma unroll
  for (int m = 1; m < 64; m <<= 1) { s += __shfl_xor(s, m); sq += __shfl_xor(sq, m); }
  __shared__ float red[8];
  const int wave = threadIdx.x >> 6, lane = threadIdx.x & 63;
  if (lane == 0) { red[wave] = s; red[4 + wave] = sq; }
  __syncthreads();
  s = red[0] + red[1] + red[2] + red[3];
  sq = red[4] + red[5] + red[6] + red[7];
  const float mean = s * (1.f / 512.f);
  const float inv = rsqrtf(sq * (1.f / 512.f) - mean * mean + kEPS);
  const float* gp = qkvg + (size_t)row * 2048 + 1536;
  const float g0 = gp[threadIdx.x], g1 = gp[threadIdx.x + 256];
  bf16_t* op = gated + (size_t)row * 512;
  op[threadIdx.x] = (bf16_t)(g0 / (1.f + expf(-g0)) * (v0 - mean) * inv);
  op[threadIdx.x + 256] = (bf16_t)(g1 / (1.f + expf(-g1)) * (v1 - mean) * inv);
}

extern "C" void kernel_launch(void* const* d_in, const int* in_sizes, int n_in,
                              void* d_out, int out_size, void* d_ws, size_t ws_size,
                              hipStream_t stream) {
  const float* x_in = (const float*)d_in[0];
  const float* Wq = (const float*)d_in[1];
  const float* bq = (const float*)d_in[2];
  const float* Wk = (const float*)d_in[3];
  const float* bk = (const float*)d_in[4];
  const float* Wv = (const float*)d_in[5];
  const float* bv = (const float*)d_in[6];
  const float* Wg = (const float*)d_in[7];
  const float* bg = (const float*)d_in[8];
  const float* Wo = (const float*)d_in[9];
  const float* bo = (const float*)d_in[10];
  const float* W1 = (const float*)d_in[11];
  const float* b1 = (const float*)d_in[12];
  const float* W2 = (const float*)d_in[13];
  const float* b2 = (const float*)d_in[14];

  char* ws = (char*)d_ws;
  bf16_t* WQKVG = (bf16_t*)(ws + OFF_WQKVG);
  bf16_t* WOt   = (bf16_t*)(ws + OFF_WO);
  bf16_t* W1t   = (bf16_t*)(ws + OFF_W1);
  bf16_t* W2t   = (bf16_t*)(ws + OFF_W2);
  float*  BQKVG = (float*)(ws + OFF_BQKVG);
  float*  TABC  = (float*)(ws + OFF_TABC);
  float*  TABS  = (float*)(ws + OFF_TABS);
  bf16_t* HLN   = (bf16_t*)(ws + OFF_HLN);
  float*  QKVG  = (float*)(ws + OFF_QKVG);
  bf16_t* QR    = (bf16_t*)(ws + OFF_QR);
  bf16_t* KR    = (bf16_t*)(ws + OFF_KR);
  bf16_t* VT    = (bf16_t*)(ws + OFF_VT);
  float*  AO    = (float*)(ws + OFF_AO);
  bf16_t* GATED = (bf16_t*)(ws + OFF_GATED);
  float*  xbuf  = (float*)d_out;

  hipMemcpyAsync(xbuf, x_in, (size_t)Mc * Cc * 4, hipMemcpyDeviceToDevice, stream);

  // ---- prep ----
  const dim3 tb(32, 8);
  const float* wsrc[4] = {Wq, Wk, Wv, Wg};
  for (int c = 0; c < 4; ++c)
    transpose_pack_k<<<dim3(Cc / 32, Cc / 32, Lc), tb, 0, stream>>>(
        wsrc[c], WQKVG + (size_t)c * Cc * Cc, Cc, Cc, (size_t)Cc * Cc, (size_t)2048 * Cc);
  transpose_pack_k<<<dim3(Cc / 32, Cc / 32, Lc), tb, 0, stream>>>(
      Wo, WOt, Cc, Cc, (size_t)Cc * Cc, (size_t)Cc * Cc);
  transpose_pack_k<<<dim3(FFNc / 32, Cc / 32, Lc), tb, 0, stream>>>(
      W1, W1t, Cc, FFNc, (size_t)Cc * FFNc, (size_t)FFNc * Cc);
  transpose_pack_k<<<dim3(Cc / 32, FFNc / 32, Lc), tb, 0, stream>>>(
      W2, W2t, FFNc, Cc, (size_t)FFNc * Cc, (size_t)Cc * FFNc);
  biaspack_k<<<32, 256, 0, stream>>>(bq, bk, bv, bg, BQKVG);
  trig_k<<<256, 256, 0, stream>>>(TABC, TABS);

  for (int l = 0; l < Lc; ++l) {
    // retention block
    ln_k<512><<<Mc, 256, 0, stream>>>(xbuf, HLN);
    gemm_k<128, 128, 64, 64, 2><<<dim3(2048 / 128, Mc / 128), 256, 0, stream>>>(
        HLN, WQKVG + (size_t)l * 2048 * 512, BQKVG + l * 2048, nullptr, QKVG, Mc, 2048, 512,
        TABC, TABS, QR, KR, VT);
    retention_k<<<256, 512, 0, stream>>>(QR, KR, VT, AO);
    postret_k<<<Mc, 256, 0, stream>>>(AO, QKVG, GATED);
    gemm_k<128, 64, 64, 32, 3><<<dim3(512 / 64, Mc / 128), 256, 0, stream>>>(
        GATED, WOt + (size_t)l * 512 * 512, bo + l * 512, xbuf, xbuf, Mc, 512, 512,
        nullptr, nullptr, nullptr, nullptr, nullptr);
    // FFN block
    ln_k<512><<<Mc, 256, 0, stream>>>(xbuf, HLN);
    gemm_k<128, 128, 64, 64, 1><<<dim3(2048 / 128, Mc / 128), 256, 0, stream>>>(
        HLN, W1t + (size_t)l * 2048 * 512, b1 + l * 2048, nullptr, QKVG, Mc, 2048, 512,
        nullptr, nullptr, nullptr, nullptr, nullptr);
    ln_k<2048><<<Mc, 256, 0, stream>>>(QKVG, HLN);
    gemm_k<128, 64, 64, 32, 3><<<dim3(512 / 64, Mc / 128), 256, 0, stream>>>(
        HLN, W2t + (size_t)l * 512 * 2048, b2 + l * 512, xbuf, xbuf, Mc, 512, 2048,
        nullptr, nullptr, nullptr, nullptr, nullptr);
  }
}

// Round 7
// 696.498 us; speedup vs baseline: 2.2891x; 1.2579x over previous
//
#include <hip/hip_runtime.h>
#include <math.h>

typedef __bf16 bf16_t;
typedef __bf16 bf16x4 __attribute__((ext_vector_type(4)));
typedef __bf16 bf16x8 __attribute__((ext_vector_type(8)));
typedef float f32x4 __attribute__((ext_vector_type(4)));

#define DEV __device__ __forceinline__

constexpr int Bc = 2, Tc = 2048, Cc = 512, Hc = 8, FFNc = 2048, Lc = 4;
constexpr int Mc = Bc * Tc;           // 4096 rows
constexpr float kSCALE = 0.125f;      // KD^-0.5, KD=64
constexpr float kEPS = 1e-6f;

// ---------------- workspace layout (bytes) ----------------
constexpr size_t OFF_WQKVG = 0;                                    // L*2048*512 bf16
constexpr size_t OFF_WO    = OFF_WQKVG + (size_t)Lc*2048*512*2;    // L*512*512 bf16
constexpr size_t OFF_W1    = OFF_WO    + (size_t)Lc*512*512*2;     // L*2048*512 bf16
constexpr size_t OFF_W2    = OFF_W1    + (size_t)Lc*2048*512*2;    // L*512*2048 bf16
constexpr size_t OFF_BQKVG = OFF_W2    + (size_t)Lc*512*2048*2;    // L*2048 f32
constexpr size_t OFF_TABC  = OFF_BQKVG + (size_t)Lc*2048*4;        // 2048*32 f32
constexpr size_t OFF_TABS  = OFF_TABC  + (size_t)Tc*32*4;
constexpr size_t OFF_HLN   = OFF_TABS  + (size_t)Tc*32*4;          // 4096*2048 bf16
constexpr size_t OFF_QKVG  = OFF_HLN   + (size_t)Mc*2048*2;        // 4096*2048 f32 (g slice + FFN h1)
constexpr size_t OFF_QR    = OFF_QKVG  + (size_t)Mc*2048*4;        // (B,H,T,64) bf16
constexpr size_t OFF_KR    = OFF_QR    + (size_t)Bc*Hc*Tc*64*2;
constexpr size_t OFF_VT    = OFF_KR    + (size_t)Bc*Hc*Tc*64*2;    // (B,H,64,T) bf16 transposed V
constexpr size_t OFF_AO    = OFF_VT    + (size_t)Bc*Hc*64*Tc*2;    // 4096*512 f32 normalized retention out
constexpr size_t OFF_GATED = OFF_AO    + (size_t)Mc*512*4;         // 4096*512 bf16

DEV float gelu_f(float x) { return 0.5f * x * (1.0f + erff(x * 0.70710678118654752f)); }

DEV void async_load16(const void* g, void* l) {
  __builtin_amdgcn_global_load_lds((const __attribute__((address_space(1))) unsigned int*)g,
                                   (__attribute__((address_space(3))) unsigned int*)l, 16, 0, 0);
}

// ---------------- weight transpose+pack: dst[n*K+k] = bf16(src[k*N+n]) ----------------
__global__ __launch_bounds__(256) void transpose_pack_k(const float* __restrict__ src, bf16_t* __restrict__ dst,
                                                        int K, int N, size_t src_lstride, size_t dst_lstride) {
  __shared__ float tile[32][33];
  src += blockIdx.z * src_lstride;
  dst += blockIdx.z * dst_lstride;
  const int n0 = blockIdx.x * 32, k0 = blockIdx.y * 32;
  const int tx = threadIdx.x, ty = threadIdx.y;  // (32,8)
#pragma unroll
  for (int j = 0; j < 32; j += 8) tile[ty + j][tx] = src[(size_t)(k0 + ty + j) * N + n0 + tx];
  __syncthreads();
#pragma unroll
  for (int j = 0; j < 32; j += 8) dst[(size_t)(n0 + ty + j) * K + k0 + tx] = (bf16_t)tile[tx][ty + j];
}

__global__ __launch_bounds__(256) void biaspack_k(const float* __restrict__ bq, const float* __restrict__ bk,
                                                  const float* __restrict__ bv, const float* __restrict__ bg,
                                                  float* __restrict__ outp) {
  const int tid = blockIdx.x * 256 + threadIdx.x;  // L*2048
  const int l = tid >> 11, n = tid & 2047;
  const float* srcs[4] = {bq, bk, bv, bg};
  outp[tid] = srcs[n >> 9][l * 512 + (n & 511)];
}

__global__ __launch_bounds__(256) void trig_k(float* __restrict__ tc, float* __restrict__ ts) {
  const int tid = blockIdx.x * 256 + threadIdx.x;  // 65536
  const int t = tid >> 5, i = tid & 31;
  const float angle = powf(10000.f, -(float)i / 31.f);
  const float a = (float)t * angle;
  tc[tid] = cosf(a);
  ts[tid] = sinf(a);
}

// ---------------- LayerNorm (no affine) fp32 in -> bf16 out ----------------
template <int NC>
__global__ __launch_bounds__(256) void ln_k(const float* __restrict__ in, bf16_t* __restrict__ out) {
  constexpr int PT = NC / 256;
  const int row = blockIdx.x;
  const float* rp = in + (size_t)row * NC;
  float v[PT], s = 0.f, sq = 0.f;
#pragma unroll
  for (int i = 0; i < PT; ++i) { v[i] = rp[threadIdx.x + i * 256]; s += v[i]; sq += v[i] * v[i]; }
#pragma unroll
  for (int m = 1; m < 64; m <<= 1) { s += __shfl_xor(s, m); sq += __shfl_xor(sq, m); }
  __shared__ float red[8];
  const int wave = threadIdx.x >> 6, lane = threadIdx.x & 63;
  if (lane == 0) { red[wave] = s; red[4 + wave] = sq; }
  __syncthreads();
  s = red[0] + red[1] + red[2] + red[3];
  sq = red[4] + red[5] + red[6] + red[7];
  const float mean = s * (1.f / NC);
  const float inv = rsqrtf(sq * (1.f / NC) - mean * mean + kEPS);
  bf16_t* op = out + (size_t)row * NC;
#pragma unroll
  for (int i = 0; i < PT; ++i) op[threadIdx.x + i * 256] = (bf16_t)((v[i] - mean) * inv);
}

// ---------------- GEMM: out(f32) = epi(A(bf16, MxK) @ Bt(bf16, NxK)^T + bias) ----------------
// Double-buffered LDS, one barrier per K-step (minimum 2-phase pipeline).
// EPI 1: gelu -> out.  EPI 3: gelu + residual -> out.
// EPI 2 (fused qkvg): gelu; region by col>>9: 0=q -> theta -> QR; 1=k -> *SCALE, theta -> KR;
//                     2=v -> VT (transposed); 3=g -> out (QKVG f32, g slice only).
template <int BM, int BN, int WM, int WN, int EPI>
__global__ __launch_bounds__(256) void gemm_k(const bf16_t* __restrict__ A, const bf16_t* __restrict__ Bt,
                                              const float* __restrict__ bias, const float* __restrict__ res,
                                              float* __restrict__ out, int M, int N, int K,
                                              const float* __restrict__ tabc, const float* __restrict__ tabs,
                                              bf16_t* __restrict__ qrp, bf16_t* __restrict__ krp,
                                              bf16_t* __restrict__ vtp) {
  constexpr int BK = 32;
  constexpr int WIN_M = WM / 16, WIN_N = WN / 16;
  __shared__ bf16_t lds[2][(BM + BN) * BK];
  const int wave = threadIdx.x >> 6, lane = threadIdx.x & 63;
  // bijective XCD swizzle (nwg % 8 == 0 for all our grids): per-XCD contiguous row-strips
  const int nwg = gridDim.x * gridDim.y;
  const int orig = blockIdx.y * gridDim.x + blockIdx.x;
  const int wg = (orig & 7) * (nwg >> 3) + (orig >> 3);
  const int bx = wg % gridDim.x, by = wg / gridDim.x;
  const int m0 = by * BM, n0 = bx * BN;
  const int wm = wave >> 1, wn = wave & 1;
  f32x4 acc[WIN_M][WIN_N] = {};
  const int lrow = lane >> 2, lcb = (lane & 3) * 8;
  const int ksub = (lane >> 4) * 8, rsub = lane & 15;

#define GSTAGE(bf_, kt_)                                                              \
  {                                                                                   \
    for (int i = wave; i < BM / 16; i += 4)                                           \
      async_load16(A + (size_t)(m0 + i * 16 + lrow) * K + (kt_) + lcb,                \
                   &lds[bf_][i * 16 * BK]);                                           \
    for (int i = wave; i < BN / 16; i += 4)                                           \
      async_load16(Bt + (size_t)(n0 + i * 16 + lrow) * K + (kt_) + lcb,               \
                   &lds[bf_][BM * BK + i * 16 * BK]);                                 \
  }

  int buf = 0;
  GSTAGE(0, 0);
  __syncthreads();
  for (int kt = 0; kt < K; kt += BK) {
    if (kt + BK < K) GSTAGE(buf ^ 1, kt + BK);
    const bf16_t* bufA = &lds[buf][0];
    const bf16_t* bufB = &lds[buf][BM * BK];
    bf16x8 af[WIN_M], bfr[WIN_N];
#pragma unroll
    for (int mi = 0; mi < WIN_M; ++mi) af[mi] = *(const bf16x8*)&bufA[(wm * WM + mi * 16 + rsub) * BK + ksub];
#pragma unroll
    for (int ni = 0; ni < WIN_N; ++ni) bfr[ni] = *(const bf16x8*)&bufB[(wn * WN + ni * 16 + rsub) * BK + ksub];
#pragma unroll
    for (int mi = 0; mi < WIN_M; ++mi)
#pragma unroll
      for (int ni = 0; ni < WIN_N; ++ni)
        acc[mi][ni] = __builtin_amdgcn_mfma_f32_16x16x32_bf16(af[mi], bfr[ni], acc[mi][ni], 0, 0, 0);
    __syncthreads();  // drains prefetch (vmcnt) + orders lds reuse
    buf ^= 1;
  }
#undef GSTAGE

#pragma unroll
  for (int mi = 0; mi < WIN_M; ++mi)
#pragma unroll
    for (int ni = 0; ni < WIN_N; ++ni) {
      const int col = n0 + wn * WN + ni * 16 + (lane & 15);
      const int row0 = m0 + wm * WM + mi * 16 + (lane >> 4) * 4;
      const float bv = bias ? bias[col] : 0.f;
      if constexpr (EPI == 2) {
        const int region = col >> 9;  // wave-uniform (each wave's 64 cols sit in one 512-region)
        if (region <= 1) {
          const int hh = (col >> 6) & 7, d = col & 63, ti = d >> 1;
          bf16_t* dst = region ? krp : qrp;
#pragma unroll
          for (int r = 0; r < 4; ++r) {
            float v = gelu_f(acc[mi][ni][r] + bv);
            if (region == 1) v *= kSCALE;
            const float p = __shfl_xor(v, 1);  // partner col c^1 (lane bit0 == col bit0)
            const int m = row0 + r, t = m & 2047, bb = m >> 11;
            const float cv = tabc[t * 32 + ti], sv = tabs[t * 32 + ti];
            const float rot = (d & 1) ? p : -p;  // rotate_every_two
            dst[((size_t)((bb * 8 + hh) * 2048 + t)) * 64 + d] = (bf16_t)(v * cv + rot * sv);
          }
        } else if (region == 2) {
          const int hh = (col >> 6) & 7, d = col & 63;
          const int m = row0, t0 = m & 2047, bb = m >> 11;
          bf16x4 pk;
#pragma unroll
          for (int r = 0; r < 4; ++r) pk[r] = (bf16_t)gelu_f(acc[mi][ni][r] + bv);
          *(bf16x4*)&vtp[((size_t)((bb * 8 + hh) * 64 + d)) * 2048 + t0] = pk;
        } else {
#pragma unroll
          for (int r = 0; r < 4; ++r)
            out[(size_t)(row0 + r) * N + col] = gelu_f(acc[mi][ni][r] + bv);
        }
      } else {
#pragma unroll
        for (int r = 0; r < 4; ++r) {
          float v = gelu_f(acc[mi][ni][r] + bv);
          if constexpr (EPI == 3) v += res[(size_t)(row0 + r) * N + col];
          out[(size_t)(row0 + r) * N + col] = v;
        }
      }
    }
}

// ---------------- retention: LDS-staged K/V, paired q-tiles, s-parity halves, XCD-local bh ----------------
// 1D grid 256: xcd=bid&7 owns bh {2*xcd, 2*xcd+1}. 512 threads = 8 waves: wave = half*4 + sub.
// Each half stages its parity tile (K+V, 16KB) into LDS via global_load_lds, double-buffered,
// one __syncthreads per step. Chunk-XOR swizzle (chunk ^= row&7) applied on the GLOBAL SOURCE
// address and again on the ds_read side (both-sides-or-neither).
__global__ __launch_bounds__(512) void retention_k(const bf16_t* __restrict__ qr, const bf16_t* __restrict__ kr,
                                                   const bf16_t* __restrict__ vt, float* __restrict__ ao) {
  const int bid = blockIdx.x;          // 0..255
  const int j = bid >> 3;              // 0..31
  const int bh = (bid & 7) * 2 + (j & 1);
  const int qp = j >> 1;               // 0..15
  const int h = bh & 7, b = bh >> 3;
  const int wave = threadIdx.x >> 6, lane = threadIdx.x & 63;
  const int sub = wave & 3, half = wave >> 2;
  const int gi = lane >> 4, li = lane & 15;
  const float dec = log1pf(-exp2f(-5.f - (float)h));
  const float d2 = dec * 1.44269504088896340736f;
  const float inv1md = exp2f(5.f + (float)h);  // 1/(1-e^dec)
  __shared__ bf16_t kv[2][2][2][64][64];  // [buf][half][K/V][row][col] (chunk-swizzled)
  __shared__ bf16_t sS[8][16][76];        // per-wave P tile (verified conflict-free)
  __shared__ float red[4][64][21];        // cross-half reduction, stride 21
  const size_t base = (size_t)bh * (size_t)Tc * 64;
  const bf16_t* vbh = vt + (size_t)bh * 64 * Tc;

  // staging source decomposition: lane covers (row = 8*rb + srow, chunk = schunk) of a 64x64 tile
  const int srow = lane >> 3;                 // 0..7
  const int schunk = (lane & 7) ^ srow;       // pre-swizzled source chunk (dest is linear)
  // fragment read offsets (bf16 elems within a [64][64] tile); row = (16-blk)+li, k-chunks gi / gi+4
  const int roff0 = li * 64 + (((gi) ^ (li & 7)) << 3);
  const int roff1 = li * 64 + (((gi + 4) ^ (li & 7)) << 3);

  float bS[4];
#pragma unroll
  for (int sc = 0; sc < 4; ++sc) bS[sc] = exp2f(-d2 * (float)(sc * 16 + li));

#define STAGE(bf_, st_)                                                                   \
  {                                                                                       \
    const bf16_t* kt_ = kr + base + (size_t)(st_) * 64 * 64;                              \
    const bf16_t* vt_ = vbh + (st_) * 64;                                                 \
    _Pragma("unroll") for (int jj = 0; jj < 2; ++jj) {                                    \
      const int rb_ = sub * 2 + jj;                                                       \
      async_load16(kt_ + (size_t)(rb_ * 8 + srow) * 64 + schunk * 8, &kv[bf_][half][0][rb_ * 8][0]); \
      async_load16(vt_ + (size_t)(rb_ * 8 + srow) * Tc + schunk * 8, &kv[bf_][half][1][rb_ * 8][0]); \
    }                                                                                     \
  }

  for (int part = 0; part < 2; ++part) {
    const int q = part ? (31 - qp) : qp;
    const int tw = q * 64 + sub * 16;
    bf16x8 qf0, qf1;
    {
      const bf16_t* qptr = qr + base + (size_t)(tw + li) * 64 + gi * 8;
      qf0 = *(const bf16x8*)qptr;
      qf1 = *(const bf16x8*)(qptr + 32);
    }
    f32x4 accv[4] = {};
    float rs[4] = {0.f, 0.f, 0.f, 0.f};

    const int nsteps = (q + 2) >> 1;   // ceil((q+1)/2), uniform across block
    int buf = 0;
    if (half <= q) STAGE(0, half);
    __syncthreads();
    for (int i = 0; i < nsteps; ++i) {
      const int st = 2 * i + half;
      const int stn = st + 2;
      if (stn <= q) STAGE(buf ^ 1, stn);
      if (st <= q) {
        const int s0g = st * 64;
        const bf16_t* kb = &kv[buf][half][0][0][0];
        const bf16_t* vb = &kv[buf][half][1][0][0];
        float aT[4];
#pragma unroll
        for (int r = 0; r < 4; ++r) aT[r] = exp2f(d2 * (float)(tw + gi * 4 + r - s0g));
#pragma unroll
        for (int sc = 0; sc < 4; ++sc) {
          const bf16x8 kf0 = *(const bf16x8*)(kb + sc * 16 * 64 + roff0);
          const bf16x8 kf1 = *(const bf16x8*)(kb + sc * 16 * 64 + roff1);
          f32x4 Sv = {};
          Sv = __builtin_amdgcn_mfma_f32_16x16x32_bf16(qf0, kf0, Sv, 0, 0, 0);
          Sv = __builtin_amdgcn_mfma_f32_16x16x32_bf16(qf1, kf1, Sv, 0, 0, 0);
          const int s_l = sc * 16 + li;
#pragma unroll
          for (int r = 0; r < 4; ++r) {
            const float w = (s0g + s_l <= tw + gi * 4 + r) ? aT[r] * bS[sc] : 0.f;
            const float val = Sv[r] * w;
            rs[r] += val;
            sS[wave][gi * 4 + r][s_l] = (bf16_t)val;
          }
        }
        const bf16x8 pa0 = *(const bf16x8*)&sS[wave][li][gi * 8];
        const bf16x8 pa1 = *(const bf16x8*)&sS[wave][li][32 + gi * 8];
#pragma unroll
        for (int dd = 0; dd < 4; ++dd) {
          const bf16x8 vb0 = *(const bf16x8*)(vb + dd * 16 * 64 + roff0);
          const bf16x8 vb1 = *(const bf16x8*)(vb + dd * 16 * 64 + roff1);
          accv[dd] = __builtin_amdgcn_mfma_f32_16x16x32_bf16(pa0, vb0, accv[dd], 0, 0, 0);
          accv[dd] = __builtin_amdgcn_mfma_f32_16x16x32_bf16(pa1, vb1, accv[dd], 0, 0, 0);
        }
      }
      __syncthreads();
      buf ^= 1;
    }

    // reduce row-sums within the 16-lane group
#pragma unroll
    for (int r = 0; r < 4; ++r) {
      float v = rs[r];
      v += __shfl_xor(v, 1); v += __shfl_xor(v, 2); v += __shfl_xor(v, 4); v += __shfl_xor(v, 8);
      rs[r] = v;
    }
    // cross-half combine via LDS, then half=0 normalizes + stores
    if (half == 1) {
      float* rp = red[sub][lane];
#pragma unroll
      for (int dd = 0; dd < 4; ++dd)
#pragma unroll
        for (int r = 0; r < 4; ++r) rp[dd * 4 + r] = accv[dd][r];
#pragma unroll
      for (int r = 0; r < 4; ++r) rp[16 + r] = rs[r];
    }
    __syncthreads();
    if (half == 0) {
      const float* rp = red[sub][lane];
#pragma unroll
      for (int r = 0; r < 4; ++r) {
        const int t = tw + gi * 4 + r;
        const float Ssum = -expm1f(dec * (float)(t + 1)) * inv1md;
        const float rt = rsqrtf(Ssum);
        const float rsv = rs[r] + rp[16 + r];
        const float den = fmaxf(fabsf(rsv * rt), 1.0f) + kEPS;
        const float scl = rt / den;
        float* op = ao + ((size_t)(b * Tc + t)) * Cc + h * 64 + li;
#pragma unroll
        for (int dd = 0; dd < 4; ++dd) op[dd * 16] = (accv[dd][r] + rp[dd * 4 + r]) * scl;
      }
    }
    __syncthreads();
  }
#undef STAGE
}

// ---------------- post-retention: LN(ao) * silu(g) -> bf16 ----------------
__global__ __launch_bounds__(256) void postret_k(const float* __restrict__ ao, const float* __restrict__ qkvg,
                                                 bf16_t* __restrict__ gated) {
  const int row = blockIdx.x;
  const float* rp = ao + (size_t)row * 512;
  float v0 = rp[threadIdx.x], v1 = rp[threadIdx.x + 256];
  float s = v0 + v1, sq = v0 * v0 + v1 * v1;
#pragma unroll
  for (int m = 1; m < 64; m <<= 1) { s += __shfl_xor(s, m); sq += __shfl_xor(sq, m); }
  __shared__ float red[8];
  const int wave = threadIdx.x >> 6, lane = threadIdx.x & 63;
  if (lane == 0) { red[wave] = s; red[4 + wave] = sq; }
  __syncthreads();
  s = red[0] + red[1] + red[2] + red[3];
  sq = red[4] + red[5] + red[6] + red[7];
  const float mean = s * (1.f / 512.f);
  const float inv = rsqrtf(sq * (1.f / 512.f) - mean * mean + kEPS);
  const float* gp = qkvg + (size_t)row * 2048 + 1536;
  const float g0 = gp[threadIdx.x], g1 = gp[threadIdx.x + 256];
  bf16_t* op = gated + (size_t)row * 512;
  op[threadIdx.x] = (bf16_t)(g0 / (1.f + expf(-g0)) * (v0 - mean) * inv);
  op[threadIdx.x + 256] = (bf16_t)(g1 / (1.f + expf(-g1)) * (v1 - mean) * inv);
}

extern "C" void kernel_launch(void* const* d_in, const int* in_sizes, int n_in,
                              void* d_out, int out_size, void* d_ws, size_t ws_size,
                              hipStream_t stream) {
  const float* x_in = (const float*)d_in[0];
  const float* Wq = (const float*)d_in[1];
  const float* bq = (const float*)d_in[2];
  const float* Wk = (const float*)d_in[3];
  const float* bk = (const float*)d_in[4];
  const float* Wv = (const float*)d_in[5];
  const float* bv = (const float*)d_in[6];
  const float* Wg = (const float*)d_in[7];
  const float* bg = (const float*)d_in[8];
  const float* Wo = (const float*)d_in[9];
  const float* bo = (const float*)d_in[10];
  const float* W1 = (const float*)d_in[11];
  const float* b1 = (const float*)d_in[12];
  const float* W2 = (const float*)d_in[13];
  const float* b2 = (const float*)d_in[14];

  char* ws = (char*)d_ws;
  bf16_t* WQKVG = (bf16_t*)(ws + OFF_WQKVG);
  bf16_t* WOt   = (bf16_t*)(ws + OFF_WO);
  bf16_t* W1t   = (bf16_t*)(ws + OFF_W1);
  bf16_t* W2t   = (bf16_t*)(ws + OFF_W2);
  float*  BQKVG = (float*)(ws + OFF_BQKVG);
  float*  TABC  = (float*)(ws + OFF_TABC);
  float*  TABS  = (float*)(ws + OFF_TABS);
  bf16_t* HLN   = (bf16_t*)(ws + OFF_HLN);
  float*  QKVG  = (float*)(ws + OFF_QKVG);
  bf16_t* QR    = (bf16_t*)(ws + OFF_QR);
  bf16_t* KR    = (bf16_t*)(ws + OFF_KR);
  bf16_t* VT    = (bf16_t*)(ws + OFF_VT);
  float*  AO    = (float*)(ws + OFF_AO);
  bf16_t* GATED = (bf16_t*)(ws + OFF_GATED);
  float*  xbuf  = (float*)d_out;

  hipMemcpyAsync(xbuf, x_in, (size_t)Mc * Cc * 4, hipMemcpyDeviceToDevice, stream);

  // ---- prep ----
  const dim3 tb(32, 8);
  const float* wsrc[4] = {Wq, Wk, Wv, Wg};
  for (int c = 0; c < 4; ++c)
    transpose_pack_k<<<dim3(Cc / 32, Cc / 32, Lc), tb, 0, stream>>>(
        wsrc[c], WQKVG + (size_t)c * Cc * Cc, Cc, Cc, (size_t)Cc * Cc, (size_t)2048 * Cc);
  transpose_pack_k<<<dim3(Cc / 32, Cc / 32, Lc), tb, 0, stream>>>(
      Wo, WOt, Cc, Cc, (size_t)Cc * Cc, (size_t)Cc * Cc);
  transpose_pack_k<<<dim3(FFNc / 32, Cc / 32, Lc), tb, 0, stream>>>(
      W1, W1t, Cc, FFNc, (size_t)Cc * FFNc, (size_t)FFNc * Cc);
  transpose_pack_k<<<dim3(Cc / 32, FFNc / 32, Lc), tb, 0, stream>>>(
      W2, W2t, FFNc, Cc, (size_t)FFNc * Cc, (size_t)Cc * FFNc);
  biaspack_k<<<32, 256, 0, stream>>>(bq, bk, bv, bg, BQKVG);
  trig_k<<<256, 256, 0, stream>>>(TABC, TABS);

  for (int l = 0; l < Lc; ++l) {
    // retention block
    ln_k<512><<<Mc, 256, 0, stream>>>(xbuf, HLN);
    gemm_k<64, 128, 32, 64, 2><<<dim3(2048 / 128, Mc / 64), 256, 0, stream>>>(
        HLN, WQKVG + (size_t)l * 2048 * 512, BQKVG + l * 2048, nullptr, QKVG, Mc, 2048, 512,
        TABC, TABS, QR, KR, VT);
    retention_k<<<256, 512, 0, stream>>>(QR, KR, VT, AO);
    postret_k<<<Mc, 256, 0, stream>>>(AO, QKVG, GATED);
    gemm_k<64, 64, 32, 32, 3><<<dim3(512 / 64, Mc / 64), 256, 0, stream>>>(
        GATED, WOt + (size_t)l * 512 * 512, bo + l * 512, xbuf, xbuf, Mc, 512, 512,
        nullptr, nullptr, nullptr, nullptr, nullptr);
    // FFN block
    ln_k<512><<<Mc, 256, 0, stream>>>(xbuf, HLN);
    gemm_k<64, 128, 32, 64, 1><<<dim3(2048 / 128, Mc / 64), 256, 0, stream>>>(
        HLN, W1t + (size_t)l * 2048 * 512, b1 + l * 2048, nullptr, QKVG, Mc, 2048, 512,
        nullptr, nullptr, nullptr, nullptr, nullptr);
    ln_k<2048><<<Mc, 256, 0, stream>>>(QKVG, HLN);
    gemm_k<64, 64, 32, 32, 3><<<dim3(512 / 64, Mc / 64), 256, 0, stream>>>(
        HLN, W2t + (size_t)l * 512 * 2048, b2 + l * 512, xbuf, xbuf, Mc, 512, 2048,
        nullptr, nullptr, nullptr, nullptr, nullptr);
  }
}

// Round 8
// 675.709 us; speedup vs baseline: 2.3595x; 1.0308x over previous
//
#include <hip/hip_runtime.h>
#include <math.h>

typedef __bf16 bf16_t;
typedef __bf16 bf16x4 __attribute__((ext_vector_type(4)));
typedef __bf16 bf16x8 __attribute__((ext_vector_type(8)));
typedef float f32x4 __attribute__((ext_vector_type(4)));

#define DEV __device__ __forceinline__

constexpr int Bc = 2, Tc = 2048, Cc = 512, Hc = 8, FFNc = 2048, Lc = 4;
constexpr int Mc = Bc * Tc;           // 4096 rows
constexpr float kSCALE = 0.125f;      // KD^-0.5, KD=64
constexpr float kEPS = 1e-6f;

// ---------------- workspace layout (bytes) ----------------
constexpr size_t OFF_WQKVG = 0;                                    // L*2048*512 bf16
constexpr size_t OFF_WO    = OFF_WQKVG + (size_t)Lc*2048*512*2;    // L*512*512 bf16
constexpr size_t OFF_W1    = OFF_WO    + (size_t)Lc*512*512*2;     // L*2048*512 bf16
constexpr size_t OFF_W2    = OFF_W1    + (size_t)Lc*2048*512*2;    // L*512*2048 bf16
constexpr size_t OFF_BQKVG = OFF_W2    + (size_t)Lc*512*2048*2;    // L*2048 f32
constexpr size_t OFF_TABC  = OFF_BQKVG + (size_t)Lc*2048*4;        // 2048*32 f32
constexpr size_t OFF_TABS  = OFF_TABC  + (size_t)Tc*32*4;
constexpr size_t OFF_HLN   = OFF_TABS  + (size_t)Tc*32*4;          // 4096*2048 bf16
constexpr size_t OFF_QKVG  = OFF_HLN   + (size_t)Mc*2048*2;        // 4096*2048 f32 (g slice + FFN h1)
constexpr size_t OFF_QR    = OFF_QKVG  + (size_t)Mc*2048*4;        // (B,H,T,64) bf16
constexpr size_t OFF_KR    = OFF_QR    + (size_t)Bc*Hc*Tc*64*2;
constexpr size_t OFF_VT    = OFF_KR    + (size_t)Bc*Hc*Tc*64*2;    // (B,H,64,T) bf16 transposed V
constexpr size_t OFF_AO    = OFF_VT    + (size_t)Bc*Hc*64*Tc*2;    // 4096*512 f32 normalized retention out
constexpr size_t OFF_GATED = OFF_AO    + (size_t)Mc*512*4;         // 4096*512 bf16

DEV float gelu_f(float x) { return 0.5f * x * (1.0f + erff(x * 0.70710678118654752f)); }

DEV void async_load16(const void* g, void* l) {
  __builtin_amdgcn_global_load_lds((const __attribute__((address_space(1))) unsigned int*)g,
                                   (__attribute__((address_space(3))) unsigned int*)l, 16, 0, 0);
}

// counted-vmcnt publish point: my batch-t loads done -> barrier -> safe for all waves
#define PIPE_WAIT_BARRIER(J_)                                        \
  asm volatile("s_waitcnt vmcnt(%0)" ::"i"(J_) : "memory");          \
  __builtin_amdgcn_s_barrier();                                      \
  __builtin_amdgcn_sched_barrier(0);

// ---------------- weight transpose+pack: dst[n*K+k] = bf16(src[k*N+n]) ----------------
__global__ __launch_bounds__(256) void transpose_pack_k(const float* __restrict__ src, bf16_t* __restrict__ dst,
                                                        int K, int N, size_t src_lstride, size_t dst_lstride) {
  __shared__ float tile[32][33];
  src += blockIdx.z * src_lstride;
  dst += blockIdx.z * dst_lstride;
  const int n0 = blockIdx.x * 32, k0 = blockIdx.y * 32;
  const int tx = threadIdx.x, ty = threadIdx.y;  // (32,8)
#pragma unroll
  for (int j = 0; j < 32; j += 8) tile[ty + j][tx] = src[(size_t)(k0 + ty + j) * N + n0 + tx];
  __syncthreads();
#pragma unroll
  for (int j = 0; j < 32; j += 8) dst[(size_t)(n0 + ty + j) * K + k0 + tx] = (bf16_t)tile[tx][ty + j];
}

__global__ __launch_bounds__(256) void biaspack_k(const float* __restrict__ bq, const float* __restrict__ bk,
                                                  const float* __restrict__ bv, const float* __restrict__ bg,
                                                  float* __restrict__ outp) {
  const int tid = blockIdx.x * 256 + threadIdx.x;  // L*2048
  const int l = tid >> 11, n = tid & 2047;
  const float* srcs[4] = {bq, bk, bv, bg};
  outp[tid] = srcs[n >> 9][l * 512 + (n & 511)];
}

__global__ __launch_bounds__(256) void trig_k(float* __restrict__ tc, float* __restrict__ ts) {
  const int tid = blockIdx.x * 256 + threadIdx.x;  // 65536
  const int t = tid >> 5, i = tid & 31;
  const float angle = powf(10000.f, -(float)i / 31.f);
  const float a = (float)t * angle;
  tc[tid] = cosf(a);
  ts[tid] = sinf(a);
}

// ---------------- LayerNorm (no affine) fp32 in -> bf16 out ----------------
template <int NC>
__global__ __launch_bounds__(256) void ln_k(const float* __restrict__ in, bf16_t* __restrict__ out) {
  constexpr int PT = NC / 256;
  const int row = blockIdx.x;
  const float* rp = in + (size_t)row * NC;
  float v[PT], s = 0.f, sq = 0.f;
#pragma unroll
  for (int i = 0; i < PT; ++i) { v[i] = rp[threadIdx.x + i * 256]; s += v[i]; sq += v[i] * v[i]; }
#pragma unroll
  for (int m = 1; m < 64; m <<= 1) { s += __shfl_xor(s, m); sq += __shfl_xor(sq, m); }
  __shared__ float red[8];
  const int wave = threadIdx.x >> 6, lane = threadIdx.x & 63;
  if (lane == 0) { red[wave] = s; red[4 + wave] = sq; }
  __syncthreads();
  s = red[0] + red[1] + red[2] + red[3];
  sq = red[4] + red[5] + red[6] + red[7];
  const float mean = s * (1.f / NC);
  const float inv = rsqrtf(sq * (1.f / NC) - mean * mean + kEPS);
  bf16_t* op = out + (size_t)row * NC;
#pragma unroll
  for (int i = 0; i < PT; ++i) op[threadIdx.x + i * 256] = (bf16_t)((v[i] - mean) * inv);
}

// ---------------- GEMM: out(f32) = epi(A(bf16, MxK) @ Bt(bf16, NxK)^T + bias) ----------------
// 3-buffer LDS pipeline, counted vmcnt(J), single raw barrier per K-step (T4).
// EPI 1: gelu -> out.  EPI 3: gelu + residual -> out.
// EPI 2 (fused qkvg): gelu; region by col>>9: 0=q -> theta -> QR; 1=k -> *SCALE, theta -> KR;
//                     2=v -> VT (transposed); 3=g -> out (QKVG f32, g slice only).
template <int BM, int BN, int WM, int WN, int EPI>
__global__ __launch_bounds__(256) void gemm_k(const bf16_t* __restrict__ A, const bf16_t* __restrict__ Bt,
                                              const float* __restrict__ bias, const float* __restrict__ res,
                                              float* __restrict__ out, int M, int N, int K,
                                              const float* __restrict__ tabc, const float* __restrict__ tabs,
                                              bf16_t* __restrict__ qrp, bf16_t* __restrict__ krp,
                                              bf16_t* __restrict__ vtp) {
  constexpr int BK = 32;
  constexpr int WIN_M = WM / 16, WIN_N = WN / 16;
  constexpr int JL = (BM + BN) / 64;  // async_load16 per wave per stage
  __shared__ bf16_t lds[3][(BM + BN) * BK];
  const int wave = threadIdx.x >> 6, lane = threadIdx.x & 63;
  // bijective XCD swizzle (nwg % 8 == 0 for all our grids): per-XCD contiguous row-strips
  const int nwg = gridDim.x * gridDim.y;
  const int orig = blockIdx.y * gridDim.x + blockIdx.x;
  const int wg = (orig & 7) * (nwg >> 3) + (orig >> 3);
  const int bx = wg % gridDim.x, by = wg / gridDim.x;
  const int m0 = by * BM, n0 = bx * BN;
  const int wm = wave >> 1, wn = wave & 1;
  f32x4 acc[WIN_M][WIN_N] = {};
  const int lrow = lane >> 2, lcb = (lane & 3) * 8;
  const int ksub = (lane >> 4) * 8, rsub = lane & 15;

#define GSTAGE(bf_, kt_)                                                              \
  {                                                                                   \
    for (int i = wave; i < BM / 16; i += 4)                                           \
      async_load16(A + (size_t)(m0 + i * 16 + lrow) * K + (kt_) + lcb,                \
                   &lds[bf_][i * 16 * BK]);                                           \
    for (int i = wave; i < BN / 16; i += 4)                                           \
      async_load16(Bt + (size_t)(n0 + i * 16 + lrow) * K + (kt_) + lcb,               \
                   &lds[bf_][BM * BK + i * 16 * BK]);                                 \
  }

  const int NT = K / BK;
  GSTAGE(0, 0);
  for (int tt = 0; tt < NT; ++tt) {
    const int ktn = (tt + 1 < NT) ? (tt + 1) * BK : (NT - 1) * BK;  // clamped restage keeps J uniform
    GSTAGE((tt + 1) % 3, ktn);
    PIPE_WAIT_BARRIER(JL);
    const bf16_t* bufA = &lds[tt % 3][0];
    const bf16_t* bufB = &lds[tt % 3][BM * BK];
    bf16x8 af[WIN_M], bfr[WIN_N];
#pragma unroll
    for (int mi = 0; mi < WIN_M; ++mi) af[mi] = *(const bf16x8*)&bufA[(wm * WM + mi * 16 + rsub) * BK + ksub];
#pragma unroll
    for (int ni = 0; ni < WIN_N; ++ni) bfr[ni] = *(const bf16x8*)&bufB[(wn * WN + ni * 16 + rsub) * BK + ksub];
#pragma unroll
    for (int mi = 0; mi < WIN_M; ++mi)
#pragma unroll
      for (int ni = 0; ni < WIN_N; ++ni)
        acc[mi][ni] = __builtin_amdgcn_mfma_f32_16x16x32_bf16(af[mi], bfr[ni], acc[mi][ni], 0, 0, 0);
  }
#undef GSTAGE
  asm volatile("s_waitcnt vmcnt(0)" ::: "memory");  // drain clamped tail loads before exit

#pragma unroll
  for (int mi = 0; mi < WIN_M; ++mi)
#pragma unroll
    for (int ni = 0; ni < WIN_N; ++ni) {
      const int col = n0 + wn * WN + ni * 16 + (lane & 15);
      const int row0 = m0 + wm * WM + mi * 16 + (lane >> 4) * 4;
      const float bv = bias ? bias[col] : 0.f;
      if constexpr (EPI == 2) {
        const int region = col >> 9;  // wave-uniform (each wave's cols sit in one 512-region)
        if (region <= 1) {
          const int hh = (col >> 6) & 7, d = col & 63, ti = d >> 1;
          bf16_t* dst = region ? krp : qrp;
#pragma unroll
          for (int r = 0; r < 4; ++r) {
            float v = gelu_f(acc[mi][ni][r] + bv);
            if (region == 1) v *= kSCALE;
            const float p = __shfl_xor(v, 1);  // partner col c^1 (lane bit0 == col bit0)
            const int m = row0 + r, t = m & 2047, bb = m >> 11;
            const float cv = tabc[t * 32 + ti], sv = tabs[t * 32 + ti];
            const float rot = (d & 1) ? p : -p;  // rotate_every_two
            dst[((size_t)((bb * 8 + hh) * 2048 + t)) * 64 + d] = (bf16_t)(v * cv + rot * sv);
          }
        } else if (region == 2) {
          const int hh = (col >> 6) & 7, d = col & 63;
          const int m = row0, t0 = m & 2047, bb = m >> 11;
          bf16x4 pk;
#pragma unroll
          for (int r = 0; r < 4; ++r) pk[r] = (bf16_t)gelu_f(acc[mi][ni][r] + bv);
          *(bf16x4*)&vtp[((size_t)((bb * 8 + hh) * 64 + d)) * 2048 + t0] = pk;
        } else {
#pragma unroll
          for (int r = 0; r < 4; ++r)
            out[(size_t)(row0 + r) * N + col] = gelu_f(acc[mi][ni][r] + bv);
        }
      } else {
#pragma unroll
        for (int r = 0; r < 4; ++r) {
          float v = gelu_f(acc[mi][ni][r] + bv);
          if constexpr (EPI == 3) v += res[(size_t)(row0 + r) * N + col];
          out[(size_t)(row0 + r) * N + col] = v;
        }
      }
    }
}

// ---------------- retention: LDS-staged K/V (3-buf counted-vmcnt pipeline), paired q-tiles ----------------
// 1D grid 256: xcd=bid&7 owns bh {2*xcd, 2*xcd+1}. 512 threads = 8 waves: wave = half*4 + sub.
// Each half stages its parity tile (K+V, 16KB) via global_load_lds; counted vmcnt(4) + raw barrier,
// never drains in-loop. Chunk-XOR swizzle on GLOBAL SOURCE + same XOR on ds_read (both-sides).
__global__ __launch_bounds__(512) void retention_k(const bf16_t* __restrict__ qr, const bf16_t* __restrict__ kr,
                                                   const bf16_t* __restrict__ vt, float* __restrict__ ao) {
  const int bid = blockIdx.x;          // 0..255
  const int j = bid >> 3;              // 0..31
  const int bh = (bid & 7) * 2 + (j & 1);
  const int qp = j >> 1;               // 0..15
  const int h = bh & 7, b = bh >> 3;
  const int wave = threadIdx.x >> 6, lane = threadIdx.x & 63;
  const int sub = wave & 3, half = wave >> 2;
  const int gi = lane >> 4, li = lane & 15;
  const float dec = log1pf(-exp2f(-5.f - (float)h));
  const float d2 = dec * 1.44269504088896340736f;
  const float inv1md = exp2f(5.f + (float)h);  // 1/(1-e^dec)
  __shared__ bf16_t kv[3][2][2][64][64];  // [buf][half][K/V][row][col] (chunk-swizzled)
  __shared__ bf16_t sS[8][16][76];        // per-wave P tile (verified conflict-free)
  __shared__ float red[4][64][21];        // cross-half reduction, stride 21
  const size_t base = (size_t)bh * (size_t)Tc * 64;
  const bf16_t* vbh = vt + (size_t)bh * 64 * Tc;

  // staging source decomposition: lane covers (row = 8*rb + srow, chunk = schunk) of a 64x64 tile
  const int srow = lane >> 3;                 // 0..7
  const int schunk = (lane & 7) ^ srow;       // pre-swizzled source chunk (dest is linear)
  // fragment read offsets; row = 16-blk + li, k-chunks gi / gi+4, same XOR on read side
  const int roff0 = li * 64 + (((gi) ^ (li & 7)) << 3);
  const int roff1 = li * 64 + (((gi + 4) ^ (li & 7)) << 3);

  float bS[4];
#pragma unroll
  for (int sc = 0; sc < 4; ++sc) bS[sc] = exp2f(-d2 * (float)(sc * 16 + li));

#define STAGE(bf_, st_)                                                                   \
  {                                                                                       \
    const bf16_t* kt_ = kr + base + (size_t)(st_) * 64 * 64;                              \
    const bf16_t* vt_ = vbh + (st_) * 64;                                                 \
    _Pragma("unroll") for (int jj = 0; jj < 2; ++jj) {                                    \
      const int rb_ = sub * 2 + jj;                                                       \
      async_load16(kt_ + (size_t)(rb_ * 8 + srow) * 64 + schunk * 8, &kv[bf_][half][0][rb_ * 8][0]); \
      async_load16(vt_ + (size_t)(rb_ * 8 + srow) * Tc + schunk * 8, &kv[bf_][half][1][rb_ * 8][0]); \
    }                                                                                     \
  }

  for (int part = 0; part < 2; ++part) {
    const int q = part ? (31 - qp) : qp;
    const int tw = q * 64 + sub * 16;
    bf16x8 qf0, qf1;
    {
      const bf16_t* qptr = qr + base + (size_t)(tw + li) * 64 + gi * 8;
      qf0 = *(const bf16x8*)qptr;
      qf1 = *(const bf16x8*)(qptr + 32);
    }
    f32x4 accv[4] = {};
    float rs[4] = {0.f, 0.f, 0.f, 0.f};

    const int nsteps = (q + 2) >> 1;   // ceil((q+1)/2), uniform across block
    STAGE(0, (half <= q ? half : 0));  // prologue batch (clamped garbage if this half idle)
    for (int i = 0; i < nsteps; ++i) {
      const int st = 2 * i + half;
      const int stn0 = st + 2;
      const int stn = (stn0 <= 31) ? stn0 : 31;  // clamped restage keeps J=4 uniform
      STAGE((i + 1) % 3, stn);
      PIPE_WAIT_BARRIER(4);
      if (st <= q) {
        const int s0g = st * 64;
        const bf16_t* kb = &kv[i % 3][half][0][0][0];
        const bf16_t* vb = &kv[i % 3][half][1][0][0];
        float aT[4];
#pragma unroll
        for (int r = 0; r < 4; ++r) aT[r] = exp2f(d2 * (float)(tw + gi * 4 + r - s0g));
#pragma unroll
        for (int sc = 0; sc < 4; ++sc) {
          const bf16x8 kf0 = *(const bf16x8*)(kb + sc * 16 * 64 + roff0);
          const bf16x8 kf1 = *(const bf16x8*)(kb + sc * 16 * 64 + roff1);
          f32x4 Sv = {};
          Sv = __builtin_amdgcn_mfma_f32_16x16x32_bf16(qf0, kf0, Sv, 0, 0, 0);
          Sv = __builtin_amdgcn_mfma_f32_16x16x32_bf16(qf1, kf1, Sv, 0, 0, 0);
          const int s_l = sc * 16 + li;
#pragma unroll
          for (int r = 0; r < 4; ++r) {
            const float w = (s0g + s_l <= tw + gi * 4 + r) ? aT[r] * bS[sc] : 0.f;
            const float val = Sv[r] * w;
            rs[r] += val;
            sS[wave][gi * 4 + r][s_l] = (bf16_t)val;
          }
        }
        const bf16x8 pa0 = *(const bf16x8*)&sS[wave][li][gi * 8];
        const bf16x8 pa1 = *(const bf16x8*)&sS[wave][li][32 + gi * 8];
#pragma unroll
        for (int dd = 0; dd < 4; ++dd) {
          const bf16x8 vb0 = *(const bf16x8*)(vb + dd * 16 * 64 + roff0);
          const bf16x8 vb1 = *(const bf16x8*)(vb + dd * 16 * 64 + roff1);
          accv[dd] = __builtin_amdgcn_mfma_f32_16x16x32_bf16(pa0, vb0, accv[dd], 0, 0, 0);
          accv[dd] = __builtin_amdgcn_mfma_f32_16x16x32_bf16(pa1, vb1, accv[dd], 0, 0, 0);
        }
      }
    }

    // reduce row-sums within the 16-lane group
#pragma unroll
    for (int r = 0; r < 4; ++r) {
      float v = rs[r];
      v += __shfl_xor(v, 1); v += __shfl_xor(v, 2); v += __shfl_xor(v, 4); v += __shfl_xor(v, 8);
      rs[r] = v;
    }
    // cross-half combine via LDS, then half=0 normalizes + stores
    // (__syncthreads drains vmcnt(0) -> clamped tail loads land before buffers are reused next part)
    if (half == 1) {
      float* rp = red[sub][lane];
#pragma unroll
      for (int dd = 0; dd < 4; ++dd)
#pragma unroll
        for (int r = 0; r < 4; ++r) rp[dd * 4 + r] = accv[dd][r];
#pragma unroll
      for (int r = 0; r < 4; ++r) rp[16 + r] = rs[r];
    }
    __syncthreads();
    if (half == 0) {
      const float* rp = red[sub][lane];
#pragma unroll
      for (int r = 0; r < 4; ++r) {
        const int t = tw + gi * 4 + r;
        const float Ssum = -expm1f(dec * (float)(t + 1)) * inv1md;
        const float rt = rsqrtf(Ssum);
        const float rsv = rs[r] + rp[16 + r];
        const float den = fmaxf(fabsf(rsv * rt), 1.0f) + kEPS;
        const float scl = rt / den;
        float* op = ao + ((size_t)(b * Tc + t)) * Cc + h * 64 + li;
#pragma unroll
        for (int dd = 0; dd < 4; ++dd) op[dd * 16] = (accv[dd][r] + rp[dd * 4 + r]) * scl;
      }
    }
    __syncthreads();
  }
#undef STAGE
}

// ---------------- post-retention: LN(ao) * silu(g) -> bf16 ----------------
__global__ __launch_bounds__(256) void postret_k(const float* __restrict__ ao, const float* __restrict__ qkvg,
                                                 bf16_t* __restrict__ gated) {
  const int row = blockIdx.x;
  const float* rp = ao + (size_t)row * 512;
  float v0 = rp[threadIdx.x], v1 = rp[threadIdx.x + 256];
  float s = v0 + v1, sq = v0 * v0 + v1 * v1;
#pragma unroll
  for (int m = 1; m < 64; m <<= 1) { s += __shfl_xor(s, m); sq += __shfl_xor(sq, m); }
  __shared__ float red[8];
  const int wave = threadIdx.x >> 6, lane = threadIdx.x & 63;
  if (lane == 0) { red[wave] = s; red[4 + wave] = sq; }
  __syncthreads();
  s = red[0] + red[1] + red[2] + red[3];
  sq = red[4] + red[5] + red[6] + red[7];
  const float mean = s * (1.f / 512.f);
  const float inv = rsqrtf(sq * (1.f / 512.f) - mean * mean + kEPS);
  const float* gp = qkvg + (size_t)row * 2048 + 1536;
  const float g0 = gp[threadIdx.x], g1 = gp[threadIdx.x + 256];
  bf16_t* op = gated + (size_t)row * 512;
  op[threadIdx.x] = (bf16_t)(g0 / (1.f + expf(-g0)) * (v0 - mean) * inv);
  op[threadIdx.x + 256] = (bf16_t)(g1 / (1.f + expf(-g1)) * (v1 - mean) * inv);
}

extern "C" void kernel_launch(void* const* d_in, const int* in_sizes, int n_in,
                              void* d_out, int out_size, void* d_ws, size_t ws_size,
                              hipStream_t stream) {
  const float* x_in = (const float*)d_in[0];
  const float* Wq = (const float*)d_in[1];
  const float* bq = (const float*)d_in[2];
  const float* Wk = (const float*)d_in[3];
  const float* bk = (const float*)d_in[4];
  const float* Wv = (const float*)d_in[5];
  const float* bv = (const float*)d_in[6];
  const float* Wg = (const float*)d_in[7];
  const float* bg = (const float*)d_in[8];
  const float* Wo = (const float*)d_in[9];
  const float* bo = (const float*)d_in[10];
  const float* W1 = (const float*)d_in[11];
  const float* b1 = (const float*)d_in[12];
  const float* W2 = (const float*)d_in[13];
  const float* b2 = (const float*)d_in[14];

  char* ws = (char*)d_ws;
  bf16_t* WQKVG = (bf16_t*)(ws + OFF_WQKVG);
  bf16_t* WOt   = (bf16_t*)(ws + OFF_WO);
  bf16_t* W1t   = (bf16_t*)(ws + OFF_W1);
  bf16_t* W2t   = (bf16_t*)(ws + OFF_W2);
  float*  BQKVG = (float*)(ws + OFF_BQKVG);
  float*  TABC  = (float*)(ws + OFF_TABC);
  float*  TABS  = (float*)(ws + OFF_TABS);
  bf16_t* HLN   = (bf16_t*)(ws + OFF_HLN);
  float*  QKVG  = (float*)(ws + OFF_QKVG);
  bf16_t* QR    = (bf16_t*)(ws + OFF_QR);
  bf16_t* KR    = (bf16_t*)(ws + OFF_KR);
  bf16_t* VT    = (bf16_t*)(ws + OFF_VT);
  float*  AO    = (float*)(ws + OFF_AO);
  bf16_t* GATED = (bf16_t*)(ws + OFF_GATED);
  float*  xbuf  = (float*)d_out;

  hipMemcpyAsync(xbuf, x_in, (size_t)Mc * Cc * 4, hipMemcpyDeviceToDevice, stream);

  // ---- prep ----
  const dim3 tb(32, 8);
  const float* wsrc[4] = {Wq, Wk, Wv, Wg};
  for (int c = 0; c < 4; ++c)
    transpose_pack_k<<<dim3(Cc / 32, Cc / 32, Lc), tb, 0, stream>>>(
        wsrc[c], WQKVG + (size_t)c * Cc * Cc, Cc, Cc, (size_t)Cc * Cc, (size_t)2048 * Cc);
  transpose_pack_k<<<dim3(Cc / 32, Cc / 32, Lc), tb, 0, stream>>>(
      Wo, WOt, Cc, Cc, (size_t)Cc * Cc, (size_t)Cc * Cc);
  transpose_pack_k<<<dim3(FFNc / 32, Cc / 32, Lc), tb, 0, stream>>>(
      W1, W1t, Cc, FFNc, (size_t)Cc * FFNc, (size_t)FFNc * Cc);
  transpose_pack_k<<<dim3(Cc / 32, FFNc / 32, Lc), tb, 0, stream>>>(
      W2, W2t, FFNc, Cc, (size_t)FFNc * Cc, (size_t)Cc * FFNc);
  biaspack_k<<<32, 256, 0, stream>>>(bq, bk, bv, bg, BQKVG);
  trig_k<<<256, 256, 0, stream>>>(TABC, TABS);

  for (int l = 0; l < Lc; ++l) {
    // retention block
    ln_k<512><<<Mc, 256, 0, stream>>>(xbuf, HLN);
    gemm_k<64, 128, 32, 64, 2><<<dim3(2048 / 128, Mc / 64), 256, 0, stream>>>(
        HLN, WQKVG + (size_t)l * 2048 * 512, BQKVG + l * 2048, nullptr, QKVG, Mc, 2048, 512,
        TABC, TABS, QR, KR, VT);
    retention_k<<<256, 512, 0, stream>>>(QR, KR, VT, AO);
    postret_k<<<Mc, 256, 0, stream>>>(AO, QKVG, GATED);
    gemm_k<64, 64, 32, 32, 3><<<dim3(512 / 64, Mc / 64), 256, 0, stream>>>(
        GATED, WOt + (size_t)l * 512 * 512, bo + l * 512, xbuf, xbuf, Mc, 512, 512,
        nullptr, nullptr, nullptr, nullptr, nullptr);
    // FFN block
    ln_k<512><<<Mc, 256, 0, stream>>>(xbuf, HLN);
    gemm_k<64, 128, 32, 64, 1><<<dim3(2048 / 128, Mc / 64), 256, 0, stream>>>(
        HLN, W1t + (size_t)l * 2048 * 512, b1 + l * 2048, nullptr, QKVG, Mc, 2048, 512,
        nullptr, nullptr, nullptr, nullptr, nullptr);
    ln_k<2048><<<Mc, 256, 0, stream>>>(QKVG, HLN);
    gemm_k<64, 64, 32, 32, 3><<<dim3(512 / 64, Mc / 64), 256, 0, stream>>>(
        HLN, W2t + (size_t)l * 512 * 2048, b2 + l * 512, xbuf, xbuf, Mc, 512, 2048,
        nullptr, nullptr, nullptr, nullptr, nullptr);
  }
}